// Round 10
// baseline (116.647 us; speedup 1.0000x reference)
//
#include <hip/hip_runtime.h>
#include <hip/hip_bf16.h>
#include <hip/hip_fp16.h>
#include <stdint.h>

#define N_   8
#define C_   256
#define H_   64
#define W_   64
#define CO_  256
#define K_   9
#define HO_  64
#define WO_  64
#define CK_  (C_ * K_)    // 2304
#define P_   (HO_ * WO_)  // 4096

#define BN   64           // p per block
#define BCO  128          // co per block (CO split across 2 blocks)
#define BK   64           // ck per K-step (2 MFMA K-slices)
#define NT   36           // K-steps: 9 taps x 4 channel-quarters
#define NTHR 512          // 8 waves

typedef __attribute__((ext_vector_type(8))) _Float16 f16x8;
typedef __attribute__((ext_vector_type(4))) float f32x4;

__device__ __forceinline__ unsigned short f2bf(float f) {
    uint32_t u = __builtin_bit_cast(uint32_t, f);
    uint32_t r = (u + 0x7FFFu + ((u >> 16) & 1u)) >> 16;
    return (unsigned short)r;
}
__device__ __forceinline__ unsigned short f2h(float f) {
    return __builtin_bit_cast(unsigned short, (_Float16)f);
}
__device__ __forceinline__ float bf2f(unsigned short u) {
    return __builtin_bit_cast(float, (uint32_t)u << 16);
}

// ================= FAST PATH (needs 17,956,864 B of d_ws) =================

// pre-pass A: x[n][c][hw] f32 -> xT[n][hw][c] f16
__global__ __launch_bounds__(256)
void transpose_x(const float* __restrict__ x, unsigned short* __restrict__ xT) {
    __shared__ float t[64][65];
    const int n  = blockIdx.z;
    const int c0 = blockIdx.y * 64;
    const int h0 = blockIdx.x * 64;
    const int tx = threadIdx.x & 63;
    const int ty = threadIdx.x >> 6;   // 0..3
    const float* xp = x + ((size_t)n * C_ + c0) * P_ + h0;
    #pragma unroll
    for (int i = 0; i < 16; ++i) {
        int c = ty * 16 + i;
        t[c][tx] = xp[(size_t)c * P_ + tx];
    }
    __syncthreads();
    unsigned short* op = xT + ((size_t)n * P_ + h0) * C_ + c0;
    #pragma unroll
    for (int i = 0; i < 16; ++i) {
        int hw = ty * 16 + i;
        op[(size_t)hw * C_ + tx] = f2h(t[tx][hw]);
    }
}

// pre-pass B: weight[co][c][k] f32 -> Wt[co][k][c] f16
__global__ __launch_bounds__(256)
void reorder_w(const float* __restrict__ w, unsigned short* __restrict__ Wt) {
    const int co = blockIdx.x;
    const int c  = threadIdx.x;
    const float* src = w + (size_t)co * CK_ + (size_t)c * K_;
    float v[9];
    #pragma unroll
    for (int k = 0; k < 9; ++k) v[k] = src[k];
    #pragma unroll
    for (int k = 0; k < 9; ++k)
        Wt[(size_t)co * CK_ + k * C_ + c] = f2h(v[k]);
}

// Raw-barrier helper: keeps in-flight vmem loads alive across the barrier
// (__syncthreads would force s_waitcnt vmcnt(0) first).
__device__ __forceinline__ void barrier_lgkm_only() {
    __builtin_amdgcn_sched_barrier(0);
    asm volatile("s_waitcnt lgkmcnt(0)" ::: "memory");
    __builtin_amdgcn_s_barrier();
    __builtin_amdgcn_sched_barrier(0);
}

// Main fused kernel. Round-10 changes vs r9:
//  - f16 everywhere on the sampled path: xT/Wt f16, bilinear combine via
//    v_pk_fma_f16 (__hfma2), MFMA 16x16x32_f16. ~16 packed ops replace ~60
//    scalar VALU per thread per iter; no cvt_pk needed (result is f16 pairs).
//  - CO split (BCO=128): LDS 38.4 KB -> grid 1024 blocks = 4 blocks/CU,
//    32 waves/CU (r9 was grid-limited at 2 blocks/CU, Occupancy 34%).
//  - keeps r9 raw-barrier counted-vmcnt pipeline + 8-slot XOR swizzle.
// launch_bounds(512,8): VGPR cap 256 >> live set (~95) — no r8-style spill.
__global__ __launch_bounds__(NTHR, 8)
void dcn_main(const unsigned short* __restrict__ xT,
              const unsigned short* __restrict__ Wt,
              const float* __restrict__ offset,
              const float* __restrict__ mask,
              float* __restrict__ out) {
    __shared__ uint2 sIdx[BN * K_];               // 4608 B: 4x u16 corner idx (write-once)
    __shared__ uint4 sWd [BN * K_];               // 9216 B: 4x dup-f16 corner weights
    __shared__ unsigned short sWs[BCO * BK];      // 16 KB (restaged per iter)
    __shared__ unsigned short sBs[BN * BK];       //  8 KB (restaged per iter)  -> 38400 B

    const int tid = threadIdx.x;
    // XCD-pin: bid%8 = XCD = batch image (both co-halves of an image stay on
    // its XCD; per-XCD set ~3.2MB fits 4MB L2).
    const int bid = blockIdx.x;
    const int n   = bid & 7;
    const int r   = bid >> 3;          // 0..127
    const int p0  = (r >> 1) * BN;
    const int co0 = (r & 1) * BCO;

    for (int e = tid; e < BN * K_; e += NTHR) {
        int pl = e / K_;
        int k  = e - pl * K_;
        int p  = p0 + pl;
        int ho = p >> 6, wo = p & 63;
        float offy = offset[(size_t)((n * 2 * K_ + 2 * k)     * P_) + p];
        float offx = offset[(size_t)((n * 2 * K_ + 2 * k + 1) * P_) + p];
        float m    = mask  [(size_t)((n * K_ + k) * P_) + p];
        float py = (float)(k / 3 + ho - 1) + offy;
        float px = (float)(k % 3 + wo - 1) + offx;
        float y0f = floorf(py), x0f = floorf(px);
        float ly = py - y0f,   lx = px - x0f;
        int y0 = (int)y0f, x0 = (int)x0f;
        int y1 = y0 + 1,   x1 = x0 + 1;
        bool vy0 = (y0 >= 0) & (y0 < H_);
        bool vy1 = (y1 >= 0) & (y1 < H_);
        bool vx0 = (x0 >= 0) & (x0 < W_);
        bool vx1 = (x1 >= 0) & (x1 < W_);
        float w00 = (1.f - ly) * (1.f - lx) * m * ((vy0 & vx0) ? 1.f : 0.f);
        float w01 = (1.f - ly) * lx         * m * ((vy0 & vx1) ? 1.f : 0.f);
        float w10 = ly * (1.f - lx)         * m * ((vy1 & vx0) ? 1.f : 0.f);
        float w11 = ly * lx                 * m * ((vy1 & vx1) ? 1.f : 0.f);
        unsigned int cy0 = (unsigned)min(max(y0, 0), H_ - 1);
        unsigned int cy1 = (unsigned)min(max(y1, 0), H_ - 1);
        unsigned int cx0 = (unsigned)min(max(x0, 0), W_ - 1);
        unsigned int cx1 = (unsigned)min(max(x1, 0), W_ - 1);
        sIdx[e] = make_uint2((cy0 * W_ + cx0) | ((cy0 * W_ + cx1) << 16),
                             (cy1 * W_ + cx0) | ((cy1 * W_ + cx1) << 16));
        // duplicated halves for v_pk_fma_f16 broadcast
        sWd[e] = make_uint4((unsigned)f2h(w00) * 0x10001u,
                            (unsigned)f2h(w01) * 0x10001u,
                            (unsigned)f2h(w10) * 0x10001u,
                            (unsigned)f2h(w11) * 0x10001u);
    }
    __syncthreads();   // params visible before prefetch(0) reads sIdx

    const unsigned short* xTn = xT + (size_t)n * P_ * C_;

    // ---- roles ----
    // sampling: (p-row, 8-channel sub-block)
    const int spl = tid >> 3;                 // 0..63
    const int cs8 = (tid & 7) * 8;            // 0..56
    char* bdst = (char*)sBs + spl * 128 + (((tid & 7) ^ (spl & 7)) << 4);
    // weight staging: 4 threads per co row, 2x 16B each
    const int wco = tid >> 2;                 // 0..127
    const int wsl = tid & 3;                  // slot wsl and wsl+4
    const int wswz = wco & 7;
    char* wrow = (char*)sWs + wco * 128;
    const unsigned short* wsrcbase = Wt + (size_t)(co0 + wco) * CK_ + wsl * 8;

    const int lane = tid & 63;
    const int wid  = tid >> 6;
    const int wm   = (wid & 3) * 32;          // wave co base within BCO (2 m-frags)
    const int wp   = (wid >> 2) * 32;         // wave p base (2 n-frags)
    const int l15  = lane & 15;
    const int l4   = lane >> 4;               // 0..3
    const int slA  = l4 ^ (l15 & 7);          // ks=0 slot; ks=1 -> ^4

    f32x4 acc[2][2] = {};

    // prefetch registers (tile t+1 in flight across both barriers)
    uint4 qa, qb, qc, qd;        // 4 bilinear corners x 8 channels (f16)
    uint4 wq0, wq1;              // 2x 16B of weight row

    // ---- prefetch tile 0 ----
    {
        const unsigned short* ws = wsrcbase;
        wq0 = *(const uint4*)(ws);
        wq1 = *(const uint4*)(ws + 32);
        uint2 id = sIdx[spl * K_];
        const unsigned short* base = xTn + cs8;
        qa = *(const uint4*)(base + ((size_t)(id.x & 0xFFFFu) << 8));
        qb = *(const uint4*)(base + ((size_t)(id.x >> 16)     << 8));
        qc = *(const uint4*)(base + ((size_t)(id.y & 0xFFFFu) << 8));
        qd = *(const uint4*)(base + ((size_t)(id.y >> 16)     << 8));
    }

    for (int t = 0; t < NT; ++t) {
        const int k = t >> 2;

        // B1: all waves' MFMA ds_reads of tile t-1 done before overwrite.
        barrier_lgkm_only();

        // consume point: tile t's prefetched loads must have landed
        asm volatile("s_waitcnt vmcnt(0)" ::: "memory");

        // ---- write-late: stage tile t from prefetched regs ----
        {
            *(uint4*)(wrow + ((wsl       ^ wswz) << 4)) = wq0;
            *(uint4*)(wrow + (((wsl + 4) ^ wswz) << 4)) = wq1;

            uint4 wv = sWd[spl * K_ + k];
            __half2 W0 = __builtin_bit_cast(__half2, wv.x);
            __half2 W1 = __builtin_bit_cast(__half2, wv.y);
            __half2 W2 = __builtin_bit_cast(__half2, wv.z);
            __half2 W3 = __builtin_bit_cast(__half2, wv.w);
            const unsigned* pa = (const unsigned*)&qa;
            const unsigned* pb = (const unsigned*)&qb;
            const unsigned* pc = (const unsigned*)&qc;
            const unsigned* pd = (const unsigned*)&qd;
            unsigned rr[4];
            #pragma unroll
            for (int h = 0; h < 4; ++h) {
                __half2 v = __hmul2(W0, __builtin_bit_cast(__half2, pa[h]));
                v = __hfma2(W1, __builtin_bit_cast(__half2, pb[h]), v);
                v = __hfma2(W2, __builtin_bit_cast(__half2, pc[h]), v);
                v = __hfma2(W3, __builtin_bit_cast(__half2, pd[h]), v);
                rr[h] = __builtin_bit_cast(unsigned, v);
            }
            *(uint4*)bdst = make_uint4(rr[0], rr[1], rr[2], rr[3]);
        }

        // ---- issue-early: prefetch tile t+1 (survives both barriers) ----
        if (t + 1 < NT) {
            const int kn  = (t + 1) >> 2;
            const int c0n = ((t + 1) & 3) * 64;
            const unsigned short* ws = wsrcbase + kn * C_ + c0n;
            wq0 = *(const uint4*)(ws);
            wq1 = *(const uint4*)(ws + 32);
            uint2 id = sIdx[spl * K_ + kn];
            const unsigned short* base = xTn + c0n + cs8;
            qa = *(const uint4*)(base + ((size_t)(id.x & 0xFFFFu) << 8));
            qb = *(const uint4*)(base + ((size_t)(id.x >> 16)     << 8));
            qc = *(const uint4*)(base + ((size_t)(id.y & 0xFFFFu) << 8));
            qd = *(const uint4*)(base + ((size_t)(id.y >> 16)     << 8));
        }

        // B2: tile t staged; do NOT drain vmcnt here.
        barrier_lgkm_only();

        // ---- MFMA: 2 K-slices x 2 m x 2 n ----
        #pragma unroll
        for (int ks = 0; ks < 2; ++ks) {
            const int sl = slA ^ (ks << 2);
            f16x8 b0 = *(const f16x8*)((const char*)sBs + (wp      + l15) * 128 + (sl << 4));
            f16x8 b1 = *(const f16x8*)((const char*)sBs + (wp + 16 + l15) * 128 + (sl << 4));
            #pragma unroll
            for (int m = 0; m < 2; ++m) {
                f16x8 a = *(const f16x8*)((const char*)sWs + (wm + m * 16 + l15) * 128 + (sl << 4));
                acc[m][0] = __builtin_amdgcn_mfma_f32_16x16x32_f16(a, b0, acc[m][0], 0, 0, 0);
                acc[m][1] = __builtin_amdgcn_mfma_f32_16x16x32_f16(a, b1, acc[m][1], 0, 0, 0);
            }
        }
    }

    float* outn = out + (size_t)n * CO_ * P_;
    #pragma unroll
    for (int m = 0; m < 2; ++m) {
        int co = co0 + wm + m * 16 + l4 * 4;
        #pragma unroll
        for (int nn = 0; nn < 2; ++nn) {
            int p = p0 + wp + nn * 16 + l15;
            #pragma unroll
            for (int rr = 0; rr < 4; ++rr) {
                outn[(size_t)(co + rr) * P_ + p] = acc[m][nn][rr];
            }
        }
    }
}

// ================= FALLBACK (round-2 kernel, zero scratch, proven pass) =================
template <int TAG>
__global__ __launch_bounds__(512, 2)
void dcn_fb(const float* __restrict__ x,
            const float* __restrict__ offset,
            const float* __restrict__ mask,
            const float* __restrict__ weight,
            float* __restrict__ out) {
    typedef __attribute__((ext_vector_type(8))) short bf16x8;
    __shared__ uint2  sIdx[128 * K_];
    __shared__ float4 sW  [128 * K_];
    __shared__ unsigned short sWs[CO_ * 32];
    __shared__ unsigned short sBs[128 * 32];

    const int tid = threadIdx.x;
    const int n  = blockIdx.y;
    const int p0 = blockIdx.x * 128;

    for (int e = tid; e < 128 * K_; e += 512) {
        int pl = e / K_;
        int k  = e - pl * K_;
        int p  = p0 + pl;
        int ho = p >> 6, wo = p & 63;
        float offy = offset[(size_t)((n * 2 * K_ + 2 * k)     * P_) + p];
        float offx = offset[(size_t)((n * 2 * K_ + 2 * k + 1) * P_) + p];
        float m    = mask  [(size_t)((n * K_ + k) * P_) + p];
        float py = (float)(k / 3 + ho - 1) + offy;
        float px = (float)(k % 3 + wo - 1) + offx;
        float y0f = floorf(py), x0f = floorf(px);
        float ly = py - y0f,   lx = px - x0f;
        int y0 = (int)y0f, x0 = (int)x0f;
        int y1 = y0 + 1,   x1 = x0 + 1;
        bool vy0 = (y0 >= 0) & (y0 < H_);
        bool vy1 = (y1 >= 0) & (y1 < H_);
        bool vx0 = (x0 >= 0) & (x0 < W_);
        bool vx1 = (x1 >= 0) & (x1 < W_);
        float w00 = (1.f - ly) * (1.f - lx) * m * ((vy0 & vx0) ? 1.f : 0.f);
        float w01 = (1.f - ly) * lx         * m * ((vy0 & vx1) ? 1.f : 0.f);
        float w10 = ly * (1.f - lx)         * m * ((vy1 & vx0) ? 1.f : 0.f);
        float w11 = ly * lx                 * m * ((vy1 & vx1) ? 1.f : 0.f);
        unsigned int cy0 = (unsigned)min(max(y0, 0), H_ - 1);
        unsigned int cy1 = (unsigned)min(max(y1, 0), H_ - 1);
        unsigned int cx0 = (unsigned)min(max(x0, 0), W_ - 1);
        unsigned int cx1 = (unsigned)min(max(x1, 0), W_ - 1);
        sIdx[e] = make_uint2((cy0 * W_ + cx0) | ((cy0 * W_ + cx1) << 16),
                             (cy1 * W_ + cx0) | ((cy1 * W_ + cx1) << 16));
        sW[e]   = make_float4(w00, w01, w10, w11);
    }

    const float* xn = x + (size_t)n * C_ * P_;
    const int pl   = tid >> 2;
    const int pl9  = pl * K_;
    const int ckb  = (tid & 3) * 8;
    const int wco  = tid >> 1;
    const int wck  = (tid & 1) * 16;

    const int lane = tid & 63;
    const int wid  = tid >> 6;
    const int wm   = (wid & 1) * 128;
    const int wp   = (wid >> 1) * 32;
    const int l15  = lane & 15;
    const int l4   = lane >> 4;

    f32x4 acc[8][2] = {};

    for (int ck0 = 0; ck0 < CK_; ck0 += 32) {
        __syncthreads();
        {
            const float4* wsrc = (const float4*)(weight + (size_t)wco * CK_ + ck0 + wck);
            float4 wa = wsrc[0], wb = wsrc[1], wc = wsrc[2], wd = wsrc[3];
            uint4 q0, q1;
            q0.x = f2bf(wa.x) | ((unsigned)f2bf(wa.y) << 16);
            q0.y = f2bf(wa.z) | ((unsigned)f2bf(wa.w) << 16);
            q0.z = f2bf(wb.x) | ((unsigned)f2bf(wb.y) << 16);
            q0.w = f2bf(wb.z) | ((unsigned)f2bf(wb.w) << 16);
            q1.x = f2bf(wc.x) | ((unsigned)f2bf(wc.y) << 16);
            q1.y = f2bf(wc.z) | ((unsigned)f2bf(wc.w) << 16);
            q1.z = f2bf(wd.x) | ((unsigned)f2bf(wd.y) << 16);
            q1.w = f2bf(wd.z) | ((unsigned)f2bf(wd.w) << 16);
            *(uint4*)&sWs[wco * 32 + wck]     = q0;
            *(uint4*)&sWs[wco * 32 + wck + 8] = q1;
        }
        {
            int ckstart = ck0 + ckb;
            int cc = ckstart / 9;
            int kk = ckstart - cc * 9;
            unsigned int packed[4];
            unsigned short colv[8];
            #pragma unroll
            for (int j = 0; j < 8; ++j) {
                int e = pl9 + kk;
                uint2  id = sIdx[e];
                float4 wv = sW[e];
                const float* xp = xn + ((size_t)cc << 12);
                float v = wv.x * xp[id.x & 0xFFFFu]
                        + wv.y * xp[id.x >> 16]
                        + wv.z * xp[id.y & 0xFFFFu]
                        + wv.w * xp[id.y >> 16];
                colv[j] = f2bf(v);
                ++kk; if (kk == 9) { kk = 0; ++cc; }
            }
            packed[0] = colv[0] | ((unsigned)colv[1] << 16);
            packed[1] = colv[2] | ((unsigned)colv[3] << 16);
            packed[2] = colv[4] | ((unsigned)colv[5] << 16);
            packed[3] = colv[6] | ((unsigned)colv[7] << 16);
            *(uint4*)&sBs[pl * 32 + ckb] = *(uint4*)packed;
        }
        __syncthreads();
        bf16x8 bfr0 = *(const bf16x8*)&sBs[(wp + l15)      * 32 + l4 * 8];
        bf16x8 bfr1 = *(const bf16x8*)&sBs[(wp + 16 + l15) * 32 + l4 * 8];
        #pragma unroll
        for (int m = 0; m < 8; ++m) {
            bf16x8 afr = *(const bf16x8*)&sWs[(wm + m * 16 + l15) * 32 + l4 * 8];
            acc[m][0] = __builtin_amdgcn_mfma_f32_16x16x32_bf16(afr, bfr0, acc[m][0], 0, 0, 0);
            acc[m][1] = __builtin_amdgcn_mfma_f32_16x16x32_bf16(afr, bfr1, acc[m][1], 0, 0, 0);
        }
    }

    float* outn = out + (size_t)n * CO_ * P_;
    #pragma unroll
    for (int m = 0; m < 8; ++m) {
        int co = wm + m * 16 + l4 * 4;
        #pragma unroll
        for (int nn = 0; nn < 2; ++nn) {
            int p = p0 + wp + nn * 16 + l15;
            #pragma unroll
            for (int rr = 0; rr < 4; ++rr) {
                outn[(size_t)(co + rr) * P_ + p] = acc[m][nn][rr];
            }
        }
    }
}

extern "C" void kernel_launch(void* const* d_in, const int* in_sizes, int n_in,
                              void* d_out, int out_size, void* d_ws, size_t ws_size,
                              hipStream_t stream) {
    const float* x      = (const float*)d_in[0];
    const float* offset = (const float*)d_in[1];
    const float* mask   = (const float*)d_in[2];
    const float* weight = (const float*)d_in[3];
    float* out = (float*)d_out;

    const size_t xT_elems = (size_t)N_ * P_ * C_;            // 8,388,608 ushort
    const size_t Wt_elems = (size_t)CO_ * CK_;               //   589,824 ushort
    const size_t need     = (xT_elems + Wt_elems) * sizeof(unsigned short); // 17,956,864 B

    if (ws_size >= need) {
        unsigned short* xT = (unsigned short*)d_ws;
        unsigned short* Wt = xT + xT_elems;
        transpose_x<<<dim3(P_ / 64, C_ / 64, N_), dim3(256), 0, stream>>>(x, xT);
        reorder_w<<<dim3(CO_), dim3(256), 0, stream>>>(weight, Wt);
        // grid: 8 n (XCD) x 64 p-tiles x 2 co-halves = 1024 blocks = 4/CU
        dcn_main<<<dim3((P_ / BN) * (CO_ / BCO) * N_), dim3(NTHR), 0, stream>>>(xT, Wt, offset, mask, out);
    } else if (ws_size >= (8u << 20)) {
        dcn_fb<1><<<dim3(P_ / 128, N_), dim3(512), 0, stream>>>(x, offset, mask, weight, out);
    } else {
        dcn_fb<0><<<dim3(P_ / 128, N_), dim3(512), 0, stream>>>(x, offset, mask, weight, out);
    }
}

// Round 11
// 84.856 us; speedup vs baseline: 1.3746x; 1.3746x over previous
//
#include <hip/hip_runtime.h>
#include <hip/hip_bf16.h>
#include <hip/hip_fp16.h>
#include <stdint.h>

#define N_   8
#define C_   256
#define H_   64
#define W_   64
#define CO_  256
#define K_   9
#define HO_  64
#define WO_  64
#define CK_  (C_ * K_)    // 2304
#define P_   (HO_ * WO_)  // 4096

#define BN   64           // p per block (fast path)
#define BK   64           // ck per K-step (2 MFMA K-slices)
#define NT   36           // K-steps: 9 taps x 4 channel-quarters
#define NTHR 512          // 8 waves

typedef __attribute__((ext_vector_type(8))) _Float16 f16x8;
typedef __attribute__((ext_vector_type(4))) float f32x4;

__device__ __forceinline__ unsigned short f2bf(float f) {
    uint32_t u = __builtin_bit_cast(uint32_t, f);
    uint32_t r = (u + 0x7FFFu + ((u >> 16) & 1u)) >> 16;
    return (unsigned short)r;
}
__device__ __forceinline__ float bf2f(unsigned short u) {
    return __builtin_bit_cast(float, (uint32_t)u << 16);
}
__device__ __forceinline__ unsigned short f2h(float f) {
    return __builtin_bit_cast(unsigned short, (_Float16)f);
}

// ================= FAST PATH (needs 17,956,864 B of d_ws) =================

// pre-pass A: x[n][c][hw] f32 -> xT[n][hw][c] f16
__global__ __launch_bounds__(256)
void transpose_x(const float* __restrict__ x, unsigned short* __restrict__ xT) {
    __shared__ float t[64][65];
    const int n  = blockIdx.z;
    const int c0 = blockIdx.y * 64;
    const int h0 = blockIdx.x * 64;
    const int tx = threadIdx.x & 63;
    const int ty = threadIdx.x >> 6;   // 0..3
    const float* xp = x + ((size_t)n * C_ + c0) * P_ + h0;
    #pragma unroll
    for (int i = 0; i < 16; ++i) {
        int c = ty * 16 + i;
        t[c][tx] = xp[(size_t)c * P_ + tx];
    }
    __syncthreads();
    unsigned short* op = xT + ((size_t)n * P_ + h0) * C_ + c0;
    #pragma unroll
    for (int i = 0; i < 16; ++i) {
        int hw = ty * 16 + i;
        op[(size_t)hw * C_ + tx] = f2h(t[tx][hw]);
    }
}

// pre-pass B: weight[co][c][k] f32 -> Wt[co][k][c] f16
__global__ __launch_bounds__(256)
void reorder_w(const float* __restrict__ w, unsigned short* __restrict__ Wt) {
    const int co = blockIdx.x;
    const int c  = threadIdx.x;
    const float* src = w + (size_t)co * CK_ + (size_t)c * K_;
    float v[9];
    #pragma unroll
    for (int k = 0; k < 9; ++k) v[k] = src[k];
    #pragma unroll
    for (int k = 0; k < 9; ++k)
        Wt[(size_t)co * CK_ + k * C_ + c] = f2h(v[k]);
}

// Raw-barrier helper: keeps in-flight vmem loads alive across the barrier
// (__syncthreads would force s_waitcnt vmcnt(0) first).
__device__ __forceinline__ void barrier_lgkm_only() {
    __builtin_amdgcn_sched_barrier(0);
    asm volatile("s_waitcnt lgkmcnt(0)" ::: "memory");
    __builtin_amdgcn_s_barrier();
    __builtin_amdgcn_sched_barrier(0);
}

// Main fused kernel: r9 structure byte-for-byte (BK=64, raw-barrier counted-vmcnt
// pipeline, 8-slot XOR swizzle, launch_bounds(512,4) — r8/r10 proved tighter
// VGPR caps spill the prefetch regs), with ONE change: the sampled path is f16.
//  - xT/Wt stored f16; bilinear combine via v_pk_fma_f16 (16 packed ops replace
//    ~60 scalar f32 ops + bf16 unpack shifts + cvt_pk)
//  - MFMA 16x16x32_f16 (same rate as bf16); accuracy improves (10-bit mantissa)
__global__ __launch_bounds__(NTHR, 4)
void dcn_main(const unsigned short* __restrict__ xT,
              const unsigned short* __restrict__ Wt,
              const float* __restrict__ offset,
              const float* __restrict__ mask,
              float* __restrict__ out) {
    __shared__ uint2 sIdx[BN * K_];               // 4608 B: 4x u16 corner idx (write-once)
    __shared__ uint4 sWd [BN * K_];               // 9216 B: 4x dup-f16 corner weights (write-once)
    __shared__ unsigned short sWs[CO_ * BK];      // 32 KB (restaged per iter)
    __shared__ unsigned short sBs[BN * BK];       //  8 KB (restaged per iter)  -> 54784 B

    const int tid = threadIdx.x;
    // XCD-pin: bid%8 = XCD = batch image; per-XCD working set ~3.2MB fits 4MB L2.
    const int bid = blockIdx.x;
    const int n   = bid & 7;
    const int p0  = (bid >> 3) * BN;

    for (int e = tid; e < BN * K_; e += NTHR) {
        int pl = e / K_;
        int k  = e - pl * K_;
        int p  = p0 + pl;
        int ho = p >> 6, wo = p & 63;
        float offy = offset[(size_t)((n * 2 * K_ + 2 * k)     * P_) + p];
        float offx = offset[(size_t)((n * 2 * K_ + 2 * k + 1) * P_) + p];
        float m    = mask  [(size_t)((n * K_ + k) * P_) + p];
        float py = (float)(k / 3 + ho - 1) + offy;
        float px = (float)(k % 3 + wo - 1) + offx;
        float y0f = floorf(py), x0f = floorf(px);
        float ly = py - y0f,   lx = px - x0f;
        int y0 = (int)y0f, x0 = (int)x0f;
        int y1 = y0 + 1,   x1 = x0 + 1;
        bool vy0 = (y0 >= 0) & (y0 < H_);
        bool vy1 = (y1 >= 0) & (y1 < H_);
        bool vx0 = (x0 >= 0) & (x0 < W_);
        bool vx1 = (x1 >= 0) & (x1 < W_);
        float w00 = (1.f - ly) * (1.f - lx) * m * ((vy0 & vx0) ? 1.f : 0.f);
        float w01 = (1.f - ly) * lx         * m * ((vy0 & vx1) ? 1.f : 0.f);
        float w10 = ly * (1.f - lx)         * m * ((vy1 & vx0) ? 1.f : 0.f);
        float w11 = ly * lx                 * m * ((vy1 & vx1) ? 1.f : 0.f);
        unsigned int cy0 = (unsigned)min(max(y0, 0), H_ - 1);
        unsigned int cy1 = (unsigned)min(max(y1, 0), H_ - 1);
        unsigned int cx0 = (unsigned)min(max(x0, 0), W_ - 1);
        unsigned int cx1 = (unsigned)min(max(x1, 0), W_ - 1);
        sIdx[e] = make_uint2((cy0 * W_ + cx0) | ((cy0 * W_ + cx1) << 16),
                             (cy1 * W_ + cx0) | ((cy1 * W_ + cx1) << 16));
        // duplicated halves for v_pk_fma_f16 broadcast
        sWd[e] = make_uint4((unsigned)f2h(w00) * 0x10001u,
                            (unsigned)f2h(w01) * 0x10001u,
                            (unsigned)f2h(w10) * 0x10001u,
                            (unsigned)f2h(w11) * 0x10001u);
    }
    __syncthreads();   // params visible before prefetch(0) reads sIdx (full drain ok, once)

    const unsigned short* xTn = xT + (size_t)n * P_ * C_;

    // ---- roles (identical to r9) ----
    const int spl = tid >> 3;                 // 0..63
    const int cs8 = (tid & 7) * 8;            // 0..56
    char* bdst = (char*)sBs + spl * 128 + (((tid & 7) ^ (spl & 7)) << 4);
    const int wco  = tid >> 1;                // 0..255
    const int wchq = (tid & 1) * 4;           // slot base 0 or 4
    const int wswz = wco & 7;
    char* wrow = (char*)sWs + wco * 128;
    const unsigned short* wsrcbase = Wt + (size_t)wco * CK_ + (tid & 1) * 32;

    const int lane = tid & 63;
    const int wid  = tid >> 6;
    const int wm   = (wid & 3) * 64;
    const int wp   = (wid >> 2) * 32;
    const int l15  = lane & 15;
    const int l4   = lane >> 4;               // 0..3
    const int slA  = l4 ^ (l15 & 7);          // ks=0 slot; ks=1 -> ^4

    f32x4 acc[4][2] = {};

    // prefetch registers (tile t+1 in flight across both barriers)
    uint4 qa, qb, qc, qd;        // 4 bilinear corners x 8 channels (f16)
    uint4 wq0, wq1, wq2, wq3;    // 64B of weight row

    // ---- prefetch tile 0 ----
    {
        const unsigned short* ws = wsrcbase;
        wq0 = *(const uint4*)(ws);
        wq1 = *(const uint4*)(ws + 8);
        wq2 = *(const uint4*)(ws + 16);
        wq3 = *(const uint4*)(ws + 24);
        uint2 id = sIdx[spl * K_];
        const unsigned short* base = xTn + cs8;
        qa = *(const uint4*)(base + ((size_t)(id.x & 0xFFFFu) << 8));
        qb = *(const uint4*)(base + ((size_t)(id.x >> 16)     << 8));
        qc = *(const uint4*)(base + ((size_t)(id.y & 0xFFFFu) << 8));
        qd = *(const uint4*)(base + ((size_t)(id.y >> 16)     << 8));
    }

    for (int t = 0; t < NT; ++t) {
        const int k = t >> 2;

        // B1: all waves' MFMA ds_reads of tile t-1 done before overwrite.
        // lgkm-only: the 8 global loads issued last iter stay in flight.
        barrier_lgkm_only();

        // consume point: prefetched loads for tile t must have landed
        asm volatile("s_waitcnt vmcnt(0)" ::: "memory");

        // ---- write-late: combine + stage tile t from prefetched regs ----
        {
            *(uint4*)(wrow + (((wchq + 0) ^ wswz) << 4)) = wq0;
            *(uint4*)(wrow + (((wchq + 1) ^ wswz) << 4)) = wq1;
            *(uint4*)(wrow + (((wchq + 2) ^ wswz) << 4)) = wq2;
            *(uint4*)(wrow + (((wchq + 3) ^ wswz) << 4)) = wq3;

            uint4 wv = sWd[spl * K_ + k];
            __half2 W0 = __builtin_bit_cast(__half2, wv.x);
            __half2 W1 = __builtin_bit_cast(__half2, wv.y);
            __half2 W2 = __builtin_bit_cast(__half2, wv.z);
            __half2 W3 = __builtin_bit_cast(__half2, wv.w);
            const unsigned* pa = (const unsigned*)&qa;
            const unsigned* pb = (const unsigned*)&qb;
            const unsigned* pc = (const unsigned*)&qc;
            const unsigned* pd = (const unsigned*)&qd;
            unsigned rr[4];
            #pragma unroll
            for (int h = 0; h < 4; ++h) {
                __half2 v = __hmul2(W0, __builtin_bit_cast(__half2, pa[h]));
                v = __hfma2(W1, __builtin_bit_cast(__half2, pb[h]), v);
                v = __hfma2(W2, __builtin_bit_cast(__half2, pc[h]), v);
                v = __hfma2(W3, __builtin_bit_cast(__half2, pd[h]), v);
                rr[h] = __builtin_bit_cast(unsigned, v);
            }
            *(uint4*)bdst = make_uint4(rr[0], rr[1], rr[2], rr[3]);
        }

        // ---- issue-early: prefetch tile t+1 (survives both barriers) ----
        if (t + 1 < NT) {
            const int kn  = (t + 1) >> 2;
            const int c0n = ((t + 1) & 3) * 64;
            const unsigned short* ws = wsrcbase + kn * C_ + c0n;
            wq0 = *(const uint4*)(ws);
            wq1 = *(const uint4*)(ws + 8);
            wq2 = *(const uint4*)(ws + 16);
            wq3 = *(const uint4*)(ws + 24);
            uint2 id = sIdx[spl * K_ + kn];
            const unsigned short* base = xTn + c0n + cs8;
            qa = *(const uint4*)(base + ((size_t)(id.x & 0xFFFFu) << 8));
            qb = *(const uint4*)(base + ((size_t)(id.x >> 16)     << 8));
            qc = *(const uint4*)(base + ((size_t)(id.y & 0xFFFFu) << 8));
            qd = *(const uint4*)(base + ((size_t)(id.y >> 16)     << 8));
        }

        // B2: tile t staged; do NOT drain vmcnt here.
        barrier_lgkm_only();

        // ---- MFMA: 2 K-slices x 4 m x 2 n ----
        #pragma unroll
        for (int ks = 0; ks < 2; ++ks) {
            const int sl = slA ^ (ks << 2);
            f16x8 b0 = *(const f16x8*)((const char*)sBs + (wp      + l15) * 128 + (sl << 4));
            f16x8 b1 = *(const f16x8*)((const char*)sBs + (wp + 16 + l15) * 128 + (sl << 4));
            #pragma unroll
            for (int m = 0; m < 4; ++m) {
                f16x8 a = *(const f16x8*)((const char*)sWs + (wm + m * 16 + l15) * 128 + (sl << 4));
                acc[m][0] = __builtin_amdgcn_mfma_f32_16x16x32_f16(a, b0, acc[m][0], 0, 0, 0);
                acc[m][1] = __builtin_amdgcn_mfma_f32_16x16x32_f16(a, b1, acc[m][1], 0, 0, 0);
            }
        }
    }

    float* outn = out + (size_t)n * CO_ * P_;
    #pragma unroll
    for (int m = 0; m < 4; ++m) {
        int co = wm + m * 16 + l4 * 4;
        #pragma unroll
        for (int nn = 0; nn < 2; ++nn) {
            int p = p0 + wp + nn * 16 + l15;
            #pragma unroll
            for (int r = 0; r < 4; ++r) {
                outn[(size_t)(co + r) * P_ + p] = acc[m][nn][r];
            }
        }
    }
}

// ================= FALLBACK (round-2 kernel, zero scratch, proven pass) =================
template <int TAG>
__global__ __launch_bounds__(512, 2)
void dcn_fb(const float* __restrict__ x,
            const float* __restrict__ offset,
            const float* __restrict__ mask,
            const float* __restrict__ weight,
            float* __restrict__ out) {
    typedef __attribute__((ext_vector_type(8))) short bf16x8;
    __shared__ uint2  sIdx[128 * K_];
    __shared__ float4 sW  [128 * K_];
    __shared__ unsigned short sWs[CO_ * 32];
    __shared__ unsigned short sBs[128 * 32];

    const int tid = threadIdx.x;
    const int n  = blockIdx.y;
    const int p0 = blockIdx.x * 128;

    for (int e = tid; e < 128 * K_; e += 512) {
        int pl = e / K_;
        int k  = e - pl * K_;
        int p  = p0 + pl;
        int ho = p >> 6, wo = p & 63;
        float offy = offset[(size_t)((n * 2 * K_ + 2 * k)     * P_) + p];
        float offx = offset[(size_t)((n * 2 * K_ + 2 * k + 1) * P_) + p];
        float m    = mask  [(size_t)((n * K_ + k) * P_) + p];
        float py = (float)(k / 3 + ho - 1) + offy;
        float px = (float)(k % 3 + wo - 1) + offx;
        float y0f = floorf(py), x0f = floorf(px);
        float ly = py - y0f,   lx = px - x0f;
        int y0 = (int)y0f, x0 = (int)x0f;
        int y1 = y0 + 1,   x1 = x0 + 1;
        bool vy0 = (y0 >= 0) & (y0 < H_);
        bool vy1 = (y1 >= 0) & (y1 < H_);
        bool vx0 = (x0 >= 0) & (x0 < W_);
        bool vx1 = (x1 >= 0) & (x1 < W_);
        float w00 = (1.f - ly) * (1.f - lx) * m * ((vy0 & vx0) ? 1.f : 0.f);
        float w01 = (1.f - ly) * lx         * m * ((vy0 & vx1) ? 1.f : 0.f);
        float w10 = ly * (1.f - lx)         * m * ((vy1 & vx0) ? 1.f : 0.f);
        float w11 = ly * lx                 * m * ((vy1 & vx1) ? 1.f : 0.f);
        unsigned int cy0 = (unsigned)min(max(y0, 0), H_ - 1);
        unsigned int cy1 = (unsigned)min(max(y1, 0), H_ - 1);
        unsigned int cx0 = (unsigned)min(max(x0, 0), W_ - 1);
        unsigned int cx1 = (unsigned)min(max(x1, 0), W_ - 1);
        sIdx[e] = make_uint2((cy0 * W_ + cx0) | ((cy0 * W_ + cx1) << 16),
                             (cy1 * W_ + cx0) | ((cy1 * W_ + cx1) << 16));
        sW[e]   = make_float4(w00, w01, w10, w11);
    }

    const float* xn = x + (size_t)n * C_ * P_;
    const int pl   = tid >> 2;
    const int pl9  = pl * K_;
    const int ckb  = (tid & 3) * 8;
    const int wco  = tid >> 1;
    const int wck  = (tid & 1) * 16;

    const int lane = tid & 63;
    const int wid  = tid >> 6;
    const int wm   = (wid & 1) * 128;
    const int wp   = (wid >> 1) * 32;
    const int l15  = lane & 15;
    const int l4   = lane >> 4;

    f32x4 acc[8][2] = {};

    for (int ck0 = 0; ck0 < CK_; ck0 += 32) {
        __syncthreads();
        {
            const float4* wsrc = (const float4*)(weight + (size_t)wco * CK_ + ck0 + wck);
            float4 wa = wsrc[0], wb = wsrc[1], wc = wsrc[2], wd = wsrc[3];
            uint4 q0, q1;
            q0.x = f2bf(wa.x) | ((unsigned)f2bf(wa.y) << 16);
            q0.y = f2bf(wa.z) | ((unsigned)f2bf(wa.w) << 16);
            q0.z = f2bf(wb.x) | ((unsigned)f2bf(wb.y) << 16);
            q0.w = f2bf(wb.z) | ((unsigned)f2bf(wb.w) << 16);
            q1.x = f2bf(wc.x) | ((unsigned)f2bf(wc.y) << 16);
            q1.y = f2bf(wc.z) | ((unsigned)f2bf(wc.w) << 16);
            q1.z = f2bf(wd.x) | ((unsigned)f2bf(wd.y) << 16);
            q1.w = f2bf(wd.z) | ((unsigned)f2bf(wd.w) << 16);
            *(uint4*)&sWs[wco * 32 + wck]     = q0;
            *(uint4*)&sWs[wco * 32 + wck + 8] = q1;
        }
        {
            int ckstart = ck0 + ckb;
            int cc = ckstart / 9;
            int kk = ckstart - cc * 9;
            unsigned int packed[4];
            unsigned short colv[8];
            #pragma unroll
            for (int j = 0; j < 8; ++j) {
                int e = pl9 + kk;
                uint2  id = sIdx[e];
                float4 wv = sW[e];
                const float* xp = xn + ((size_t)cc << 12);
                float v = wv.x * xp[id.x & 0xFFFFu]
                        + wv.y * xp[id.x >> 16]
                        + wv.z * xp[id.y & 0xFFFFu]
                        + wv.w * xp[id.y >> 16];
                colv[j] = f2bf(v);
                ++kk; if (kk == 9) { kk = 0; ++cc; }
            }
            packed[0] = colv[0] | ((unsigned)colv[1] << 16);
            packed[1] = colv[2] | ((unsigned)colv[3] << 16);
            packed[2] = colv[4] | ((unsigned)colv[5] << 16);
            packed[3] = colv[6] | ((unsigned)colv[7] << 16);
            *(uint4*)&sBs[pl * 32 + ckb] = *(uint4*)packed;
        }
        __syncthreads();
        bf16x8 bfr0 = *(const bf16x8*)&sBs[(wp + l15)      * 32 + l4 * 8];
        bf16x8 bfr1 = *(const bf16x8*)&sBs[(wp + 16 + l15) * 32 + l4 * 8];
        #pragma unroll
        for (int m = 0; m < 8; ++m) {
            bf16x8 afr = *(const bf16x8*)&sWs[(wm + m * 16 + l15) * 32 + l4 * 8];
            acc[m][0] = __builtin_amdgcn_mfma_f32_16x16x32_bf16(afr, bfr0, acc[m][0], 0, 0, 0);
            acc[m][1] = __builtin_amdgcn_mfma_f32_16x16x32_bf16(afr, bfr1, acc[m][1], 0, 0, 0);
        }
    }

    float* outn = out + (size_t)n * CO_ * P_;
    #pragma unroll
    for (int m = 0; m < 8; ++m) {
        int co = wm + m * 16 + l4 * 4;
        #pragma unroll
        for (int nn = 0; nn < 2; ++nn) {
            int p = p0 + wp + nn * 16 + l15;
            #pragma unroll
            for (int r = 0; r < 4; ++r) {
                outn[(size_t)(co + r) * P_ + p] = acc[m][nn][r];
            }
        }
    }
}

extern "C" void kernel_launch(void* const* d_in, const int* in_sizes, int n_in,
                              void* d_out, int out_size, void* d_ws, size_t ws_size,
                              hipStream_t stream) {
    const float* x      = (const float*)d_in[0];
    const float* offset = (const float*)d_in[1];
    const float* mask   = (const float*)d_in[2];
    const float* weight = (const float*)d_in[3];
    float* out = (float*)d_out;

    const size_t xT_elems = (size_t)N_ * P_ * C_;            // 8,388,608 ushort
    const size_t Wt_elems = (size_t)CO_ * CK_;               //   589,824 ushort
    const size_t need     = (xT_elems + Wt_elems) * sizeof(unsigned short); // 17,956,864 B

    if (ws_size >= need) {
        unsigned short* xT = (unsigned short*)d_ws;
        unsigned short* Wt = xT + xT_elems;
        transpose_x<<<dim3(P_ / 64, C_ / 64, N_), dim3(256), 0, stream>>>(x, xT);
        reorder_w<<<dim3(CO_), dim3(256), 0, stream>>>(weight, Wt);
        dcn_main<<<dim3((P_ / BN) * N_), dim3(NTHR), 0, stream>>>(xT, Wt, offset, mask, out);
    } else if (ws_size >= (8u << 20)) {
        dcn_fb<1><<<dim3(P_ / 128, N_), dim3(512), 0, stream>>>(x, offset, mask, weight, out);
    } else {
        dcn_fb<0><<<dim3(P_ / 128, N_), dim3(512), 0, stream>>>(x, offset, mask, weight, out);
    }
}

// Round 12
// 83.871 us; speedup vs baseline: 1.3908x; 1.0117x over previous
//
#include <hip/hip_runtime.h>
#include <hip/hip_bf16.h>
#include <hip/hip_fp16.h>
#include <stdint.h>

#define N_   8
#define C_   256
#define H_   64
#define W_   64
#define CO_  256
#define K_   9
#define HO_  64
#define WO_  64
#define CK_  (C_ * K_)    // 2304
#define P_   (HO_ * WO_)  // 4096

#define BN   128          // p per block
#define BK   64           // ck per K-step (2 MFMA K-slices)
#define NT   36           // K-steps: 9 taps x 4 channel-quarters
#define NTHR 512          // 8 waves

typedef __attribute__((ext_vector_type(8))) _Float16 f16x8;
typedef __attribute__((ext_vector_type(4))) float f32x4;

__device__ __forceinline__ unsigned short f2bf(float f) {
    uint32_t u = __builtin_bit_cast(uint32_t, f);
    uint32_t r = (u + 0x7FFFu + ((u >> 16) & 1u)) >> 16;
    return (unsigned short)r;
}
__device__ __forceinline__ float bf2f(unsigned short u) {
    return __builtin_bit_cast(float, (uint32_t)u << 16);
}
__device__ __forceinline__ unsigned short f2h(float f) {
    return __builtin_bit_cast(unsigned short, (_Float16)f);
}

// ================= FAST PATH (needs 17,956,864 B of d_ws) =================

// pre-pass A: x[n][c][hw] f32 -> xT[n][hw][c] f16
__global__ __launch_bounds__(256)
void transpose_x(const float* __restrict__ x, unsigned short* __restrict__ xT) {
    __shared__ float t[64][65];
    const int n  = blockIdx.z;
    const int c0 = blockIdx.y * 64;
    const int h0 = blockIdx.x * 64;
    const int tx = threadIdx.x & 63;
    const int ty = threadIdx.x >> 6;   // 0..3
    const float* xp = x + ((size_t)n * C_ + c0) * P_ + h0;
    #pragma unroll
    for (int i = 0; i < 16; ++i) {
        int c = ty * 16 + i;
        t[c][tx] = xp[(size_t)c * P_ + tx];
    }
    __syncthreads();
    unsigned short* op = xT + ((size_t)n * P_ + h0) * C_ + c0;
    #pragma unroll
    for (int i = 0; i < 16; ++i) {
        int hw = ty * 16 + i;
        op[(size_t)hw * C_ + tx] = f2h(t[tx][hw]);
    }
}

// pre-pass B: weight[co][c][k] f32 -> Wt[co][k][c] f16
__global__ __launch_bounds__(256)
void reorder_w(const float* __restrict__ w, unsigned short* __restrict__ Wt) {
    const int co = blockIdx.x;
    const int c  = threadIdx.x;
    const float* src = w + (size_t)co * CK_ + (size_t)c * K_;
    float v[9];
    #pragma unroll
    for (int k = 0; k < 9; ++k) v[k] = src[k];
    #pragma unroll
    for (int k = 0; k < 9; ++k)
        Wt[(size_t)co * CK_ + k * C_ + c] = f2h(v[k]);
}

// Raw-barrier helper: keeps in-flight vmem loads alive across the barrier
// (__syncthreads would force s_waitcnt vmcnt(0) first).
__device__ __forceinline__ void barrier_lgkm_only() {
    __builtin_amdgcn_sched_barrier(0);
    asm volatile("s_waitcnt lgkmcnt(0)" ::: "memory");
    __builtin_amdgcn_s_barrier();
    __builtin_amdgcn_sched_barrier(0);
}

// packed bilinear combine of one u32 (2 f16 channels) per corner
#define COMB(dst, A, B, Cc, D) do {                                   \
    __half2 _v = __hmul2(W0, __builtin_bit_cast(__half2, (A)));       \
    _v = __hfma2(W1, __builtin_bit_cast(__half2, (B)), _v);           \
    _v = __hfma2(W2, __builtin_bit_cast(__half2, (Cc)), _v);          \
    _v = __hfma2(W3, __builtin_bit_cast(__half2, (D)), _v);           \
    (dst) = __builtin_bit_cast(unsigned, _v); } while (0)

// Main fused kernel, round 12: 64x64 per-wave output tiles to cut per-output
// LDS-pipe traffic (r11 post-mortem: LDS unit ~2100cy/iter/CU was the critical
// path; 64x64 tiles read 16 b128 per 16 frags vs 12 per 8 = 2/3 cost, and
// halve barrier count per output). Block = 256co x 128p, grid 256 = 1 blk/CU.
// Keeps: r9 raw-barrier counted-vmcnt pipeline, 8-slot XOR swizzle, f16
// sampled path (r11: VALUBusy 33->16). launch_bounds(512,2): live set ~140
// VGPR; r8/r10 proved caps below the live set spill catastrophically.
__global__ __launch_bounds__(NTHR, 2)
void dcn_main(const unsigned short* __restrict__ xT,
              const unsigned short* __restrict__ Wt,
              const float* __restrict__ offset,
              const float* __restrict__ mask,
              float* __restrict__ out) {
    __shared__ uint2 sIdx[BN * K_];               //  9216 B: 4x u16 corner idx (write-once)
    __shared__ uint4 sWd [BN * K_];               // 18432 B: 4x dup-f16 corner weights (write-once)
    __shared__ unsigned short sWs[CO_ * BK];      // 32 KB (restaged per iter)
    __shared__ unsigned short sBs[BN * BK];       // 16 KB (restaged per iter)  -> 76800 B

    const int tid = threadIdx.x;
    // XCD-pin: bid%8 = XCD = batch image; per-XCD set ~3.2MB fits 4MB L2.
    const int bid = blockIdx.x;
    const int n   = bid & 7;
    const int p0  = (bid >> 3) * BN;   // 32 p-tiles per image

    for (int e = tid; e < BN * K_; e += NTHR) {
        int pl = e / K_;
        int k  = e - pl * K_;
        int p  = p0 + pl;
        int ho = p >> 6, wo = p & 63;
        float offy = offset[(size_t)((n * 2 * K_ + 2 * k)     * P_) + p];
        float offx = offset[(size_t)((n * 2 * K_ + 2 * k + 1) * P_) + p];
        float m    = mask  [(size_t)((n * K_ + k) * P_) + p];
        float py = (float)(k / 3 + ho - 1) + offy;
        float px = (float)(k % 3 + wo - 1) + offx;
        float y0f = floorf(py), x0f = floorf(px);
        float ly = py - y0f,   lx = px - x0f;
        int y0 = (int)y0f, x0 = (int)x0f;
        int y1 = y0 + 1,   x1 = x0 + 1;
        bool vy0 = (y0 >= 0) & (y0 < H_);
        bool vy1 = (y1 >= 0) & (y1 < H_);
        bool vx0 = (x0 >= 0) & (x0 < W_);
        bool vx1 = (x1 >= 0) & (x1 < W_);
        float w00 = (1.f - ly) * (1.f - lx) * m * ((vy0 & vx0) ? 1.f : 0.f);
        float w01 = (1.f - ly) * lx         * m * ((vy0 & vx1) ? 1.f : 0.f);
        float w10 = ly * (1.f - lx)         * m * ((vy1 & vx0) ? 1.f : 0.f);
        float w11 = ly * lx                 * m * ((vy1 & vx1) ? 1.f : 0.f);
        unsigned int cy0 = (unsigned)min(max(y0, 0), H_ - 1);
        unsigned int cy1 = (unsigned)min(max(y1, 0), H_ - 1);
        unsigned int cx0 = (unsigned)min(max(x0, 0), W_ - 1);
        unsigned int cx1 = (unsigned)min(max(x1, 0), W_ - 1);
        sIdx[e] = make_uint2((cy0 * W_ + cx0) | ((cy0 * W_ + cx1) << 16),
                             (cy1 * W_ + cx0) | ((cy1 * W_ + cx1) << 16));
        sWd[e] = make_uint4((unsigned)f2h(w00) * 0x10001u,
                            (unsigned)f2h(w01) * 0x10001u,
                            (unsigned)f2h(w10) * 0x10001u,
                            (unsigned)f2h(w11) * 0x10001u);
    }
    __syncthreads();   // params visible before prefetch(0) reads sIdx

    const unsigned short* xTn = xT + (size_t)n * P_ * C_;

    // ---- roles ----
    // sampling: thread -> (p-row, 16-channel sub-block)
    const int spl  = tid >> 2;                // 0..127
    const int cs16 = (tid & 3) * 16;          // 0,16,32,48
    const int bsw  = spl & 7;
    char* bdst0 = (char*)sBs + spl * 128 + ((((tid & 3) * 2)     ^ bsw) << 4);
    char* bdst1 = (char*)sBs + spl * 128 + ((((tid & 3) * 2 + 1) ^ bsw) << 4);
    // weight staging: thread -> (co row, 64B half-row), 4x 16B slots
    const int wco  = tid >> 1;                // 0..255
    const int wchq = (tid & 1) * 4;           // slot base 0 or 4
    const int wswz = wco & 7;
    char* wrow = (char*)sWs + wco * 128;
    const unsigned short* wsrcbase = Wt + (size_t)wco * CK_ + (tid & 1) * 32;

    const int lane = tid & 63;
    const int wid  = tid >> 6;
    const int wm   = (wid & 3) * 64;          // 4 co-groups
    const int wp   = (wid >> 2) * 64;         // 2 p-groups
    const int l15  = lane & 15;
    const int l4   = lane >> 4;               // 0..3
    const int slA  = l4 ^ (l15 & 7);          // ks=0 slot; ks=1 -> ^4

    f32x4 acc[4][4] = {};

    // prefetch registers (tile t+1 in flight across both barriers)
    uint4 qa0, qa1, qb0, qb1, qc0, qc1, qd0, qd1;  // 4 corners x 16 f16
    uint4 wq0, wq1, wq2, wq3;                      // 64B of weight row

    // ---- prefetch tile 0 ----
    {
        const unsigned short* ws = wsrcbase;
        wq0 = *(const uint4*)(ws);
        wq1 = *(const uint4*)(ws + 8);
        wq2 = *(const uint4*)(ws + 16);
        wq3 = *(const uint4*)(ws + 24);
        uint2 id = sIdx[spl * K_];
        const unsigned short* base = xTn + cs16;
        const unsigned short* ba = base + ((size_t)(id.x & 0xFFFFu) << 8);
        const unsigned short* bb = base + ((size_t)(id.x >> 16)     << 8);
        const unsigned short* bc = base + ((size_t)(id.y & 0xFFFFu) << 8);
        const unsigned short* bd = base + ((size_t)(id.y >> 16)     << 8);
        qa0 = *(const uint4*)(ba); qa1 = *(const uint4*)(ba + 8);
        qb0 = *(const uint4*)(bb); qb1 = *(const uint4*)(bb + 8);
        qc0 = *(const uint4*)(bc); qc1 = *(const uint4*)(bc + 8);
        qd0 = *(const uint4*)(bd); qd1 = *(const uint4*)(bd + 8);
    }

    for (int t = 0; t < NT; ++t) {
        const int k = t >> 2;

        // B1: all waves' MFMA ds_reads of tile t-1 done before overwrite.
        // lgkm-only: the 12 global loads issued last iter stay in flight.
        barrier_lgkm_only();

        // consume point: prefetched loads for tile t must have landed
        asm volatile("s_waitcnt vmcnt(0)" ::: "memory");

        // ---- write-late: combine + stage tile t from prefetched regs ----
        {
            *(uint4*)(wrow + (((wchq + 0) ^ wswz) << 4)) = wq0;
            *(uint4*)(wrow + (((wchq + 1) ^ wswz) << 4)) = wq1;
            *(uint4*)(wrow + (((wchq + 2) ^ wswz) << 4)) = wq2;
            *(uint4*)(wrow + (((wchq + 3) ^ wswz) << 4)) = wq3;

            uint4 wv = sWd[spl * K_ + k];
            __half2 W0 = __builtin_bit_cast(__half2, wv.x);
            __half2 W1 = __builtin_bit_cast(__half2, wv.y);
            __half2 W2 = __builtin_bit_cast(__half2, wv.z);
            __half2 W3 = __builtin_bit_cast(__half2, wv.w);
            uint4 r0, r1;
            COMB(r0.x, qa0.x, qb0.x, qc0.x, qd0.x);
            COMB(r0.y, qa0.y, qb0.y, qc0.y, qd0.y);
            COMB(r0.z, qa0.z, qb0.z, qc0.z, qd0.z);
            COMB(r0.w, qa0.w, qb0.w, qc0.w, qd0.w);
            COMB(r1.x, qa1.x, qb1.x, qc1.x, qd1.x);
            COMB(r1.y, qa1.y, qb1.y, qc1.y, qd1.y);
            COMB(r1.z, qa1.z, qb1.z, qc1.z, qd1.z);
            COMB(r1.w, qa1.w, qb1.w, qc1.w, qd1.w);
            *(uint4*)bdst0 = r0;
            *(uint4*)bdst1 = r1;
        }

        // ---- issue-early: prefetch tile t+1 (survives both barriers) ----
        if (t + 1 < NT) {
            const int kn  = (t + 1) >> 2;
            const int c0n = ((t + 1) & 3) * 64;
            const unsigned short* ws = wsrcbase + kn * C_ + c0n;
            wq0 = *(const uint4*)(ws);
            wq1 = *(const uint4*)(ws + 8);
            wq2 = *(const uint4*)(ws + 16);
            wq3 = *(const uint4*)(ws + 24);
            uint2 id = sIdx[spl * K_ + kn];
            const unsigned short* base = xTn + c0n + cs16;
            const unsigned short* ba = base + ((size_t)(id.x & 0xFFFFu) << 8);
            const unsigned short* bb = base + ((size_t)(id.x >> 16)     << 8);
            const unsigned short* bc = base + ((size_t)(id.y & 0xFFFFu) << 8);
            const unsigned short* bd = base + ((size_t)(id.y >> 16)     << 8);
            qa0 = *(const uint4*)(ba); qa1 = *(const uint4*)(ba + 8);
            qb0 = *(const uint4*)(bb); qb1 = *(const uint4*)(bb + 8);
            qc0 = *(const uint4*)(bc); qc1 = *(const uint4*)(bc + 8);
            qd0 = *(const uint4*)(bd); qd1 = *(const uint4*)(bd + 8);
        }

        // B2: tile t staged; do NOT drain vmcnt here.
        barrier_lgkm_only();

        // ---- MFMA: 2 K-slices x 4 m x 4 n ----
        #pragma unroll
        for (int ks = 0; ks < 2; ++ks) {
            const int sl = slA ^ (ks << 2);
            f16x8 b0 = *(const f16x8*)((const char*)sBs + (wp      + l15) * 128 + (sl << 4));
            f16x8 b1 = *(const f16x8*)((const char*)sBs + (wp + 16 + l15) * 128 + (sl << 4));
            f16x8 b2 = *(const f16x8*)((const char*)sBs + (wp + 32 + l15) * 128 + (sl << 4));
            f16x8 b3 = *(const f16x8*)((const char*)sBs + (wp + 48 + l15) * 128 + (sl << 4));
            #pragma unroll
            for (int m = 0; m < 4; ++m) {
                f16x8 a = *(const f16x8*)((const char*)sWs + (wm + m * 16 + l15) * 128 + (sl << 4));
                acc[m][0] = __builtin_amdgcn_mfma_f32_16x16x32_f16(a, b0, acc[m][0], 0, 0, 0);
                acc[m][1] = __builtin_amdgcn_mfma_f32_16x16x32_f16(a, b1, acc[m][1], 0, 0, 0);
                acc[m][2] = __builtin_amdgcn_mfma_f32_16x16x32_f16(a, b2, acc[m][2], 0, 0, 0);
                acc[m][3] = __builtin_amdgcn_mfma_f32_16x16x32_f16(a, b3, acc[m][3], 0, 0, 0);
            }
        }
    }

    float* outn = out + (size_t)n * CO_ * P_;
    #pragma unroll
    for (int m = 0; m < 4; ++m) {
        int co = wm + m * 16 + l4 * 4;
        #pragma unroll
        for (int nn = 0; nn < 4; ++nn) {
            int p = p0 + wp + nn * 16 + l15;
            #pragma unroll
            for (int r = 0; r < 4; ++r) {
                outn[(size_t)(co + r) * P_ + p] = acc[m][nn][r];
            }
        }
    }
}

// ================= FALLBACK (round-2 kernel, zero scratch, proven pass) =================
template <int TAG>
__global__ __launch_bounds__(512, 2)
void dcn_fb(const float* __restrict__ x,
            const float* __restrict__ offset,
            const float* __restrict__ mask,
            const float* __restrict__ weight,
            float* __restrict__ out) {
    typedef __attribute__((ext_vector_type(8))) short bf16x8;
    __shared__ uint2  sIdx[128 * K_];
    __shared__ float4 sW  [128 * K_];
    __shared__ unsigned short sWs[CO_ * 32];
    __shared__ unsigned short sBs[128 * 32];

    const int tid = threadIdx.x;
    const int n  = blockIdx.y;
    const int p0 = blockIdx.x * 128;

    for (int e = tid; e < 128 * K_; e += 512) {
        int pl = e / K_;
        int k  = e - pl * K_;
        int p  = p0 + pl;
        int ho = p >> 6, wo = p & 63;
        float offy = offset[(size_t)((n * 2 * K_ + 2 * k)     * P_) + p];
        float offx = offset[(size_t)((n * 2 * K_ + 2 * k + 1) * P_) + p];
        float m    = mask  [(size_t)((n * K_ + k) * P_) + p];
        float py = (float)(k / 3 + ho - 1) + offy;
        float px = (float)(k % 3 + wo - 1) + offx;
        float y0f = floorf(py), x0f = floorf(px);
        float ly = py - y0f,   lx = px - x0f;
        int y0 = (int)y0f, x0 = (int)x0f;
        int y1 = y0 + 1,   x1 = x0 + 1;
        bool vy0 = (y0 >= 0) & (y0 < H_);
        bool vy1 = (y1 >= 0) & (y1 < H_);
        bool vx0 = (x0 >= 0) & (x0 < W_);
        bool vx1 = (x1 >= 0) & (x1 < W_);
        float w00 = (1.f - ly) * (1.f - lx) * m * ((vy0 & vx0) ? 1.f : 0.f);
        float w01 = (1.f - ly) * lx         * m * ((vy0 & vx1) ? 1.f : 0.f);
        float w10 = ly * (1.f - lx)         * m * ((vy1 & vx0) ? 1.f : 0.f);
        float w11 = ly * lx                 * m * ((vy1 & vx1) ? 1.f : 0.f);
        unsigned int cy0 = (unsigned)min(max(y0, 0), H_ - 1);
        unsigned int cy1 = (unsigned)min(max(y1, 0), H_ - 1);
        unsigned int cx0 = (unsigned)min(max(x0, 0), W_ - 1);
        unsigned int cx1 = (unsigned)min(max(x1, 0), W_ - 1);
        sIdx[e] = make_uint2((cy0 * W_ + cx0) | ((cy0 * W_ + cx1) << 16),
                             (cy1 * W_ + cx0) | ((cy1 * W_ + cx1) << 16));
        sW[e]   = make_float4(w00, w01, w10, w11);
    }

    const float* xn = x + (size_t)n * C_ * P_;
    const int pl   = tid >> 2;
    const int pl9  = pl * K_;
    const int ckb  = (tid & 3) * 8;
    const int wco  = tid >> 1;
    const int wck  = (tid & 1) * 16;

    const int lane = tid & 63;
    const int wid  = tid >> 6;
    const int wm   = (wid & 1) * 128;
    const int wp   = (wid >> 1) * 32;
    const int l15  = lane & 15;
    const int l4   = lane >> 4;

    f32x4 acc[8][2] = {};

    for (int ck0 = 0; ck0 < CK_; ck0 += 32) {
        __syncthreads();
        {
            const float4* wsrc = (const float4*)(weight + (size_t)wco * CK_ + ck0 + wck);
            float4 wa = wsrc[0], wb = wsrc[1], wc = wsrc[2], wd = wsrc[3];
            uint4 q0, q1;
            q0.x = f2bf(wa.x) | ((unsigned)f2bf(wa.y) << 16);
            q0.y = f2bf(wa.z) | ((unsigned)f2bf(wa.w) << 16);
            q0.z = f2bf(wb.x) | ((unsigned)f2bf(wb.y) << 16);
            q0.w = f2bf(wb.z) | ((unsigned)f2bf(wb.w) << 16);
            q1.x = f2bf(wc.x) | ((unsigned)f2bf(wc.y) << 16);
            q1.y = f2bf(wc.z) | ((unsigned)f2bf(wc.w) << 16);
            q1.z = f2bf(wd.x) | ((unsigned)f2bf(wd.y) << 16);
            q1.w = f2bf(wd.z) | ((unsigned)f2bf(wd.w) << 16);
            *(uint4*)&sWs[wco * 32 + wck]     = q0;
            *(uint4*)&sWs[wco * 32 + wck + 8] = q1;
        }
        {
            int ckstart = ck0 + ckb;
            int cc = ckstart / 9;
            int kk = ckstart - cc * 9;
            unsigned int packed[4];
            unsigned short colv[8];
            #pragma unroll
            for (int j = 0; j < 8; ++j) {
                int e = pl9 + kk;
                uint2  id = sIdx[e];
                float4 wv = sW[e];
                const float* xp = xn + ((size_t)cc << 12);
                float v = wv.x * xp[id.x & 0xFFFFu]
                        + wv.y * xp[id.x >> 16]
                        + wv.z * xp[id.y & 0xFFFFu]
                        + wv.w * xp[id.y >> 16];
                colv[j] = f2bf(v);
                ++kk; if (kk == 9) { kk = 0; ++cc; }
            }
            packed[0] = colv[0] | ((unsigned)colv[1] << 16);
            packed[1] = colv[2] | ((unsigned)colv[3] << 16);
            packed[2] = colv[4] | ((unsigned)colv[5] << 16);
            packed[3] = colv[6] | ((unsigned)colv[7] << 16);
            *(uint4*)&sBs[pl * 32 + ckb] = *(uint4*)packed;
        }
        __syncthreads();
        bf16x8 bfr0 = *(const bf16x8*)&sBs[(wp + l15)      * 32 + l4 * 8];
        bf16x8 bfr1 = *(const bf16x8*)&sBs[(wp + 16 + l15) * 32 + l4 * 8];
        #pragma unroll
        for (int m = 0; m < 8; ++m) {
            bf16x8 afr = *(const bf16x8*)&sWs[(wm + m * 16 + l15) * 32 + l4 * 8];
            acc[m][0] = __builtin_amdgcn_mfma_f32_16x16x32_bf16(afr, bfr0, acc[m][0], 0, 0, 0);
            acc[m][1] = __builtin_amdgcn_mfma_f32_16x16x32_bf16(afr, bfr1, acc[m][1], 0, 0, 0);
        }
    }

    float* outn = out + (size_t)n * CO_ * P_;
    #pragma unroll
    for (int m = 0; m < 8; ++m) {
        int co = wm + m * 16 + l4 * 4;
        #pragma unroll
        for (int nn = 0; nn < 2; ++nn) {
            int p = p0 + wp + nn * 16 + l15;
            #pragma unroll
            for (int r = 0; r < 4; ++r) {
                outn[(size_t)(co + r) * P_ + p] = acc[m][nn][r];
            }
        }
    }
}

extern "C" void kernel_launch(void* const* d_in, const int* in_sizes, int n_in,
                              void* d_out, int out_size, void* d_ws, size_t ws_size,
                              hipStream_t stream) {
    const float* x      = (const float*)d_in[0];
    const float* offset = (const float*)d_in[1];
    const float* mask   = (const float*)d_in[2];
    const float* weight = (const float*)d_in[3];
    float* out = (float*)d_out;

    const size_t xT_elems = (size_t)N_ * P_ * C_;            // 8,388,608 ushort
    const size_t Wt_elems = (size_t)CO_ * CK_;               //   589,824 ushort
    const size_t need     = (xT_elems + Wt_elems) * sizeof(unsigned short); // 17,956,864 B

    if (ws_size >= need) {
        unsigned short* xT = (unsigned short*)d_ws;
        unsigned short* Wt = xT + xT_elems;
        transpose_x<<<dim3(P_ / 64, C_ / 64, N_), dim3(256), 0, stream>>>(x, xT);
        reorder_w<<<dim3(CO_), dim3(256), 0, stream>>>(weight, Wt);
        // grid: 8 n (XCD-pin) x 32 p-tiles = 256 blocks = 1 block/CU
        dcn_main<<<dim3((P_ / BN) * N_), dim3(NTHR), 0, stream>>>(xT, Wt, offset, mask, out);
    } else if (ws_size >= (8u << 20)) {
        dcn_fb<1><<<dim3(P_ / 128, N_), dim3(512), 0, stream>>>(x, offset, mask, weight, out);
    } else {
        dcn_fb<0><<<dim3(P_ / 128, N_), dim3(512), 0, stream>>>(x, offset, mask, weight, out);
    }
}

// Round 13
// 72.287 us; speedup vs baseline: 1.6137x; 1.1603x over previous
//
#include <hip/hip_runtime.h>
#include <hip/hip_bf16.h>
#include <hip/hip_fp16.h>
#include <stdint.h>

#define N_   8
#define C_   256
#define H_   64
#define W_   64
#define CO_  256
#define K_   9
#define HO_  64
#define WO_  64
#define CK_  (C_ * K_)    // 2304
#define P_   (HO_ * WO_)  // 4096

#define BN   128          // p per block
#define BK   64           // ck per K-step (2 MFMA K-slices)
#define NT   36           // K-steps: 9 taps x 4 channel-quarters
#define NTHR 512          // 8 waves

typedef __attribute__((ext_vector_type(8))) _Float16 f16x8;
typedef __attribute__((ext_vector_type(4))) float f32x4;

__device__ __forceinline__ unsigned short f2bf(float f) {
    uint32_t u = __builtin_bit_cast(uint32_t, f);
    uint32_t r = (u + 0x7FFFu + ((u >> 16) & 1u)) >> 16;
    return (unsigned short)r;
}
__device__ __forceinline__ float bf2f(unsigned short u) {
    return __builtin_bit_cast(float, (uint32_t)u << 16);
}
__device__ __forceinline__ unsigned short f2h(float f) {
    return __builtin_bit_cast(unsigned short, (_Float16)f);
}

// ================= FAST PATH (needs 17,956,864 B of d_ws) =================

// pre-pass A: x[n][c][hw] f32 -> xT[n][hw][c] f16
__global__ __launch_bounds__(256)
void transpose_x(const float* __restrict__ x, unsigned short* __restrict__ xT) {
    __shared__ float t[64][65];
    const int n  = blockIdx.z;
    const int c0 = blockIdx.y * 64;
    const int h0 = blockIdx.x * 64;
    const int tx = threadIdx.x & 63;
    const int ty = threadIdx.x >> 6;   // 0..3
    const float* xp = x + ((size_t)n * C_ + c0) * P_ + h0;
    #pragma unroll
    for (int i = 0; i < 16; ++i) {
        int c = ty * 16 + i;
        t[c][tx] = xp[(size_t)c * P_ + tx];
    }
    __syncthreads();
    unsigned short* op = xT + ((size_t)n * P_ + h0) * C_ + c0;
    #pragma unroll
    for (int i = 0; i < 16; ++i) {
        int hw = ty * 16 + i;
        op[(size_t)hw * C_ + tx] = f2h(t[tx][hw]);
    }
}

// pre-pass B: weight[co][c][k] f32 -> Wt[co][k][c] f16
__global__ __launch_bounds__(256)
void reorder_w(const float* __restrict__ w, unsigned short* __restrict__ Wt) {
    const int co = blockIdx.x;
    const int c  = threadIdx.x;
    const float* src = w + (size_t)co * CK_ + (size_t)c * K_;
    float v[9];
    #pragma unroll
    for (int k = 0; k < 9; ++k) v[k] = src[k];
    #pragma unroll
    for (int k = 0; k < 9; ++k)
        Wt[(size_t)co * CK_ + k * C_ + c] = f2h(v[k]);
}

// Raw-barrier helper: keeps in-flight vmem loads alive across the barrier
// (__syncthreads would force s_waitcnt vmcnt(0) first).
__device__ __forceinline__ void barrier_lgkm_only() {
    __builtin_amdgcn_sched_barrier(0);
    asm volatile("s_waitcnt lgkmcnt(0)" ::: "memory");
    __builtin_amdgcn_s_barrier();
    __builtin_amdgcn_sched_barrier(0);
}

// packed bilinear combine of one u32 (2 f16 channels) per corner
#define COMB(dst, A, B, Cc, D) do {                                   \
    __half2 _v = __hmul2(W0, __builtin_bit_cast(__half2, (A)));       \
    _v = __hfma2(W1, __builtin_bit_cast(__half2, (B)), _v);           \
    _v = __hfma2(W2, __builtin_bit_cast(__half2, (Cc)), _v);          \
    _v = __hfma2(W3, __builtin_bit_cast(__half2, (D)), _v);           \
    (dst) = __builtin_bit_cast(unsigned, _v); } while (0)

// Round 13: LDS DOUBLE-BUFFER -> ONE barrier per K-step (r12 post-mortem:
// ~2200cy/iter was the 2-barrier phase structure itself; stage and MFMA were
// hard-serialized). Now iter t: barrier; read tile-t frags from buf[t&1];
// stage tile t+1 into buf[(t+1)&1] (different buffer -> no second barrier);
// MFMA. ds_writes+combine co-schedule with MFMAs (separate pipes).
// Keeps: 64x64 wave tiles, raw lgkm-only barriers, counted-vmcnt reg
// prefetch, 8-slot XOR swizzle, f16 sampled path. LDS 126KB -> 1 block/CU.
__global__ __launch_bounds__(NTHR, 2)
void dcn_main(const unsigned short* __restrict__ xT,
              const unsigned short* __restrict__ Wt,
              const float* __restrict__ offset,
              const float* __restrict__ mask,
              float* __restrict__ out) {
    __shared__ uint2 sIdx[BN * K_];               //  9216 B (write-once)
    __shared__ uint4 sWd [BN * K_];               // 18432 B (write-once)
    __shared__ unsigned short sWs[2][CO_ * BK];   // 64 KB double-buffered
    __shared__ unsigned short sBs[2][BN * BK];    // 32 KB double-buffered -> 125952 B

    const int tid = threadIdx.x;
    // XCD-pin: bid%8 = XCD = batch image; per-XCD set ~3.2MB fits 4MB L2.
    const int bid = blockIdx.x;
    const int n   = bid & 7;
    const int p0  = (bid >> 3) * BN;   // 32 p-tiles per image

    for (int e = tid; e < BN * K_; e += NTHR) {
        int pl = e / K_;
        int k  = e - pl * K_;
        int p  = p0 + pl;
        int ho = p >> 6, wo = p & 63;
        float offy = offset[(size_t)((n * 2 * K_ + 2 * k)     * P_) + p];
        float offx = offset[(size_t)((n * 2 * K_ + 2 * k + 1) * P_) + p];
        float m    = mask  [(size_t)((n * K_ + k) * P_) + p];
        float py = (float)(k / 3 + ho - 1) + offy;
        float px = (float)(k % 3 + wo - 1) + offx;
        float y0f = floorf(py), x0f = floorf(px);
        float ly = py - y0f,   lx = px - x0f;
        int y0 = (int)y0f, x0 = (int)x0f;
        int y1 = y0 + 1,   x1 = x0 + 1;
        bool vy0 = (y0 >= 0) & (y0 < H_);
        bool vy1 = (y1 >= 0) & (y1 < H_);
        bool vx0 = (x0 >= 0) & (x0 < W_);
        bool vx1 = (x1 >= 0) & (x1 < W_);
        float w00 = (1.f - ly) * (1.f - lx) * m * ((vy0 & vx0) ? 1.f : 0.f);
        float w01 = (1.f - ly) * lx         * m * ((vy0 & vx1) ? 1.f : 0.f);
        float w10 = ly * (1.f - lx)         * m * ((vy1 & vx0) ? 1.f : 0.f);
        float w11 = ly * lx                 * m * ((vy1 & vx1) ? 1.f : 0.f);
        unsigned int cy0 = (unsigned)min(max(y0, 0), H_ - 1);
        unsigned int cy1 = (unsigned)min(max(y1, 0), H_ - 1);
        unsigned int cx0 = (unsigned)min(max(x0, 0), W_ - 1);
        unsigned int cx1 = (unsigned)min(max(x1, 0), W_ - 1);
        sIdx[e] = make_uint2((cy0 * W_ + cx0) | ((cy0 * W_ + cx1) << 16),
                             (cy1 * W_ + cx0) | ((cy1 * W_ + cx1) << 16));
        sWd[e] = make_uint4((unsigned)f2h(w00) * 0x10001u,
                            (unsigned)f2h(w01) * 0x10001u,
                            (unsigned)f2h(w10) * 0x10001u,
                            (unsigned)f2h(w11) * 0x10001u);
    }
    __syncthreads();   // params visible before prefetch(0) reads sIdx

    const unsigned short* xTn = xT + (size_t)n * P_ * C_;

    // ---- roles ----
    const int spl  = tid >> 2;                // 0..127 : sampled p-row
    const int cs16 = (tid & 3) * 16;          // channel sub-block
    const int bsw  = spl & 7;
    const int boff0 = spl * 128 + ((((tid & 3) * 2)     ^ bsw) << 4);
    const int boff1 = spl * 128 + ((((tid & 3) * 2 + 1) ^ bsw) << 4);
    const int wco  = tid >> 1;                // 0..255 : weight co row
    const int wchq = (tid & 1) * 4;
    const int wswz = wco & 7;
    const int woff = wco * 128;
    const unsigned short* wsrcbase = Wt + (size_t)wco * CK_ + (tid & 1) * 32;

    const int lane = tid & 63;
    const int wid  = tid >> 6;
    const int wm   = (wid & 3) * 64;          // 4 co-groups
    const int wp   = (wid >> 2) * 64;         // 2 p-groups
    const int l15  = lane & 15;
    const int l4   = lane >> 4;
    const int slA  = l4 ^ (l15 & 7);          // ks=0 slot; ks=1 -> ^4

    f32x4 acc[4][4] = {};

    // prefetch registers (one tile ahead in regs, in flight across the barrier)
    uint4 qa0, qa1, qb0, qb1, qc0, qc1, qd0, qd1;
    uint4 wq0, wq1, wq2, wq3;

#define PREF(TT) {                                                        \
        const int kn  = (TT) >> 2;                                        \
        const int c0n = ((TT) & 3) * 64;                                  \
        const unsigned short* ws = wsrcbase + kn * C_ + c0n;              \
        wq0 = *(const uint4*)(ws);                                        \
        wq1 = *(const uint4*)(ws + 8);                                    \
        wq2 = *(const uint4*)(ws + 16);                                   \
        wq3 = *(const uint4*)(ws + 24);                                   \
        uint2 id = sIdx[spl * K_ + kn];                                   \
        const unsigned short* base = xTn + c0n + cs16;                    \
        const unsigned short* ba = base + ((size_t)(id.x & 0xFFFFu) << 8);\
        const unsigned short* bb = base + ((size_t)(id.x >> 16)     << 8);\
        const unsigned short* bc = base + ((size_t)(id.y & 0xFFFFu) << 8);\
        const unsigned short* bd = base + ((size_t)(id.y >> 16)     << 8);\
        qa0 = *(const uint4*)(ba); qa1 = *(const uint4*)(ba + 8);         \
        qb0 = *(const uint4*)(bb); qb1 = *(const uint4*)(bb + 8);         \
        qc0 = *(const uint4*)(bc); qc1 = *(const uint4*)(bc + 8);         \
        qd0 = *(const uint4*)(bd); qd1 = *(const uint4*)(bd + 8);         \
    }

#define STAGE(TT, WB, BB) {                                               \
        asm volatile("s_waitcnt vmcnt(0)" ::: "memory");                  \
        char* wrB = (char*)(WB) + woff;                                   \
        *(uint4*)(wrB + (((wchq + 0) ^ wswz) << 4)) = wq0;                \
        *(uint4*)(wrB + (((wchq + 1) ^ wswz) << 4)) = wq1;                \
        *(uint4*)(wrB + (((wchq + 2) ^ wswz) << 4)) = wq2;                \
        *(uint4*)(wrB + (((wchq + 3) ^ wswz) << 4)) = wq3;                \
        uint4 wv = sWd[spl * K_ + ((TT) >> 2)];                           \
        __half2 W0 = __builtin_bit_cast(__half2, wv.x);                   \
        __half2 W1 = __builtin_bit_cast(__half2, wv.y);                   \
        __half2 W2 = __builtin_bit_cast(__half2, wv.z);                   \
        __half2 W3 = __builtin_bit_cast(__half2, wv.w);                   \
        uint4 r0, r1;                                                     \
        COMB(r0.x, qa0.x, qb0.x, qc0.x, qd0.x);                           \
        COMB(r0.y, qa0.y, qb0.y, qc0.y, qd0.y);                           \
        COMB(r0.z, qa0.z, qb0.z, qc0.z, qd0.z);                           \
        COMB(r0.w, qa0.w, qb0.w, qc0.w, qd0.w);                           \
        COMB(r1.x, qa1.x, qb1.x, qc1.x, qd1.x);                           \
        COMB(r1.y, qa1.y, qb1.y, qc1.y, qd1.y);                           \
        COMB(r1.z, qa1.z, qb1.z, qc1.z, qd1.z);                           \
        COMB(r1.w, qa1.w, qb1.w, qc1.w, qd1.w);                           \
        *(uint4*)((char*)(BB) + boff0) = r0;                              \
        *(uint4*)((char*)(BB) + boff1) = r1;                              \
    }

    // ---- prologue: tile 0 -> regs -> buf0; tile 1 -> regs ----
    PREF(0)
    STAGE(0, sWs[0], sBs[0])
    PREF(1)

    for (int t = 0; t < NT; ++t) {
        const int br = t & 1;
        const int bw = br ^ 1;
        const char* wR = (const char*)sWs[br];
        const char* bR = (const char*)sBs[br];

        // single barrier: buf[br] writes (last iter) visible; buf[bw] reads
        // (last iter's MFMA) complete. In-flight global loads survive.
        barrier_lgkm_only();

        // ks=0 fragment reads issued first (in flight during stage's vmcnt wait)
        f16x8 a0[2], a1[2], a2[2], a3[2], b0[2], b1[2], b2[2], b3[2];
        {
            const int sl = slA;
            b0[0] = *(const f16x8*)(bR + (wp      + l15) * 128 + (sl << 4));
            b1[0] = *(const f16x8*)(bR + (wp + 16 + l15) * 128 + (sl << 4));
            b2[0] = *(const f16x8*)(bR + (wp + 32 + l15) * 128 + (sl << 4));
            b3[0] = *(const f16x8*)(bR + (wp + 48 + l15) * 128 + (sl << 4));
            a0[0] = *(const f16x8*)(wR + (wm      + l15) * 128 + (sl << 4));
            a1[0] = *(const f16x8*)(wR + (wm + 16 + l15) * 128 + (sl << 4));
            a2[0] = *(const f16x8*)(wR + (wm + 32 + l15) * 128 + (sl << 4));
            a3[0] = *(const f16x8*)(wR + (wm + 48 + l15) * 128 + (sl << 4));
        }

        // stage tile t+1 into the write buffer (no barrier needed after:
        // writes target bw, MFMA reads target br)
        if (t + 1 < NT) {
            if (br) { STAGE(t + 1, sWs[0], sBs[0]) }
            else    { STAGE(t + 1, sWs[1], sBs[1]) }
            if (t + 2 < NT) PREF(t + 2)
        }

        // ks=1 fragment reads
        {
            const int sl = slA ^ 4;
            b0[1] = *(const f16x8*)(bR + (wp      + l15) * 128 + (sl << 4));
            b1[1] = *(const f16x8*)(bR + (wp + 16 + l15) * 128 + (sl << 4));
            b2[1] = *(const f16x8*)(bR + (wp + 32 + l15) * 128 + (sl << 4));
            b3[1] = *(const f16x8*)(bR + (wp + 48 + l15) * 128 + (sl << 4));
            a0[1] = *(const f16x8*)(wR + (wm      + l15) * 128 + (sl << 4));
            a1[1] = *(const f16x8*)(wR + (wm + 16 + l15) * 128 + (sl << 4));
            a2[1] = *(const f16x8*)(wR + (wm + 32 + l15) * 128 + (sl << 4));
            a3[1] = *(const f16x8*)(wR + (wm + 48 + l15) * 128 + (sl << 4));
        }

        // MFMA: 2 K-slices x 4 m x 4 n — co-schedules with the ds_writes above
        #pragma unroll
        for (int ks = 0; ks < 2; ++ks) {
            acc[0][0] = __builtin_amdgcn_mfma_f32_16x16x32_f16(a0[ks], b0[ks], acc[0][0], 0, 0, 0);
            acc[0][1] = __builtin_amdgcn_mfma_f32_16x16x32_f16(a0[ks], b1[ks], acc[0][1], 0, 0, 0);
            acc[0][2] = __builtin_amdgcn_mfma_f32_16x16x32_f16(a0[ks], b2[ks], acc[0][2], 0, 0, 0);
            acc[0][3] = __builtin_amdgcn_mfma_f32_16x16x32_f16(a0[ks], b3[ks], acc[0][3], 0, 0, 0);
            acc[1][0] = __builtin_amdgcn_mfma_f32_16x16x32_f16(a1[ks], b0[ks], acc[1][0], 0, 0, 0);
            acc[1][1] = __builtin_amdgcn_mfma_f32_16x16x32_f16(a1[ks], b1[ks], acc[1][1], 0, 0, 0);
            acc[1][2] = __builtin_amdgcn_mfma_f32_16x16x32_f16(a1[ks], b2[ks], acc[1][2], 0, 0, 0);
            acc[1][3] = __builtin_amdgcn_mfma_f32_16x16x32_f16(a1[ks], b3[ks], acc[1][3], 0, 0, 0);
            acc[2][0] = __builtin_amdgcn_mfma_f32_16x16x32_f16(a2[ks], b0[ks], acc[2][0], 0, 0, 0);
            acc[2][1] = __builtin_amdgcn_mfma_f32_16x16x32_f16(a2[ks], b1[ks], acc[2][1], 0, 0, 0);
            acc[2][2] = __builtin_amdgcn_mfma_f32_16x16x32_f16(a2[ks], b2[ks], acc[2][2], 0, 0, 0);
            acc[2][3] = __builtin_amdgcn_mfma_f32_16x16x32_f16(a2[ks], b3[ks], acc[2][3], 0, 0, 0);
            acc[3][0] = __builtin_amdgcn_mfma_f32_16x16x32_f16(a3[ks], b0[ks], acc[3][0], 0, 0, 0);
            acc[3][1] = __builtin_amdgcn_mfma_f32_16x16x32_f16(a3[ks], b1[ks], acc[3][1], 0, 0, 0);
            acc[3][2] = __builtin_amdgcn_mfma_f32_16x16x32_f16(a3[ks], b2[ks], acc[3][2], 0, 0, 0);
            acc[3][3] = __builtin_amdgcn_mfma_f32_16x16x32_f16(a3[ks], b3[ks], acc[3][3], 0, 0, 0);
        }
    }
#undef PREF
#undef STAGE

    float* outn = out + (size_t)n * CO_ * P_;
    #pragma unroll
    for (int m = 0; m < 4; ++m) {
        int co = wm + m * 16 + l4 * 4;
        #pragma unroll
        for (int nn = 0; nn < 4; ++nn) {
            int p = p0 + wp + nn * 16 + l15;
            #pragma unroll
            for (int r = 0; r < 4; ++r) {
                outn[(size_t)(co + r) * P_ + p] = acc[m][nn][r];
            }
        }
    }
}

// ================= FALLBACK (round-2 kernel, zero scratch, proven pass) =================
template <int TAG>
__global__ __launch_bounds__(512, 2)
void dcn_fb(const float* __restrict__ x,
            const float* __restrict__ offset,
            const float* __restrict__ mask,
            const float* __restrict__ weight,
            float* __restrict__ out) {
    typedef __attribute__((ext_vector_type(8))) short bf16x8;
    __shared__ uint2  sIdx[128 * K_];
    __shared__ float4 sW  [128 * K_];
    __shared__ unsigned short sWs[CO_ * 32];
    __shared__ unsigned short sBs[128 * 32];

    const int tid = threadIdx.x;
    const int n  = blockIdx.y;
    const int p0 = blockIdx.x * 128;

    for (int e = tid; e < 128 * K_; e += 512) {
        int pl = e / K_;
        int k  = e - pl * K_;
        int p  = p0 + pl;
        int ho = p >> 6, wo = p & 63;
        float offy = offset[(size_t)((n * 2 * K_ + 2 * k)     * P_) + p];
        float offx = offset[(size_t)((n * 2 * K_ + 2 * k + 1) * P_) + p];
        float m    = mask  [(size_t)((n * K_ + k) * P_) + p];
        float py = (float)(k / 3 + ho - 1) + offy;
        float px = (float)(k % 3 + wo - 1) + offx;
        float y0f = floorf(py), x0f = floorf(px);
        float ly = py - y0f,   lx = px - x0f;
        int y0 = (int)y0f, x0 = (int)x0f;
        int y1 = y0 + 1,   x1 = x0 + 1;
        bool vy0 = (y0 >= 0) & (y0 < H_);
        bool vy1 = (y1 >= 0) & (y1 < H_);
        bool vx0 = (x0 >= 0) & (x0 < W_);
        bool vx1 = (x1 >= 0) & (x1 < W_);
        float w00 = (1.f - ly) * (1.f - lx) * m * ((vy0 & vx0) ? 1.f : 0.f);
        float w01 = (1.f - ly) * lx         * m * ((vy0 & vx1) ? 1.f : 0.f);
        float w10 = ly * (1.f - lx)         * m * ((vy1 & vx0) ? 1.f : 0.f);
        float w11 = ly * lx                 * m * ((vy1 & vx1) ? 1.f : 0.f);
        unsigned int cy0 = (unsigned)min(max(y0, 0), H_ - 1);
        unsigned int cy1 = (unsigned)min(max(y1, 0), H_ - 1);
        unsigned int cx0 = (unsigned)min(max(x0, 0), W_ - 1);
        unsigned int cx1 = (unsigned)min(max(x1, 0), W_ - 1);
        sIdx[e] = make_uint2((cy0 * W_ + cx0) | ((cy0 * W_ + cx1) << 16),
                             (cy1 * W_ + cx0) | ((cy1 * W_ + cx1) << 16));
        sW[e]   = make_float4(w00, w01, w10, w11);
    }

    const float* xn = x + (size_t)n * C_ * P_;
    const int pl   = tid >> 2;
    const int pl9  = pl * K_;
    const int ckb  = (tid & 3) * 8;
    const int wco  = tid >> 1;
    const int wck  = (tid & 1) * 16;

    const int lane = tid & 63;
    const int wid  = tid >> 6;
    const int wm   = (wid & 1) * 128;
    const int wp   = (wid >> 1) * 32;
    const int l15  = lane & 15;
    const int l4   = lane >> 4;

    f32x4 acc[8][2] = {};

    for (int ck0 = 0; ck0 < CK_; ck0 += 32) {
        __syncthreads();
        {
            const float4* wsrc = (const float4*)(weight + (size_t)wco * CK_ + ck0 + wck);
            float4 wa = wsrc[0], wb = wsrc[1], wc = wsrc[2], wd = wsrc[3];
            uint4 q0, q1;
            q0.x = f2bf(wa.x) | ((unsigned)f2bf(wa.y) << 16);
            q0.y = f2bf(wa.z) | ((unsigned)f2bf(wa.w) << 16);
            q0.z = f2bf(wb.x) | ((unsigned)f2bf(wb.y) << 16);
            q0.w = f2bf(wb.z) | ((unsigned)f2bf(wb.w) << 16);
            q1.x = f2bf(wc.x) | ((unsigned)f2bf(wc.y) << 16);
            q1.y = f2bf(wc.z) | ((unsigned)f2bf(wc.w) << 16);
            q1.z = f2bf(wd.x) | ((unsigned)f2bf(wd.y) << 16);
            q1.w = f2bf(wd.z) | ((unsigned)f2bf(wd.w) << 16);
            *(uint4*)&sWs[wco * 32 + wck]     = q0;
            *(uint4*)&sWs[wco * 32 + wck + 8] = q1;
        }
        {
            int ckstart = ck0 + ckb;
            int cc = ckstart / 9;
            int kk = ckstart - cc * 9;
            unsigned int packed[4];
            unsigned short colv[8];
            #pragma unroll
            for (int j = 0; j < 8; ++j) {
                int e = pl9 + kk;
                uint2  id = sIdx[e];
                float4 wv = sW[e];
                const float* xp = xn + ((size_t)cc << 12);
                float v = wv.x * xp[id.x & 0xFFFFu]
                        + wv.y * xp[id.x >> 16]
                        + wv.z * xp[id.y & 0xFFFFu]
                        + wv.w * xp[id.y >> 16];
                colv[j] = f2bf(v);
                ++kk; if (kk == 9) { kk = 0; ++cc; }
            }
            packed[0] = colv[0] | ((unsigned)colv[1] << 16);
            packed[1] = colv[2] | ((unsigned)colv[3] << 16);
            packed[2] = colv[4] | ((unsigned)colv[5] << 16);
            packed[3] = colv[6] | ((unsigned)colv[7] << 16);
            *(uint4*)&sBs[pl * 32 + ckb] = *(uint4*)packed;
        }
        __syncthreads();
        bf16x8 bfr0 = *(const bf16x8*)&sBs[(wp + l15)      * 32 + l4 * 8];
        bf16x8 bfr1 = *(const bf16x8*)&sBs[(wp + 16 + l15) * 32 + l4 * 8];
        #pragma unroll
        for (int m = 0; m < 8; ++m) {
            bf16x8 afr = *(const bf16x8*)&sWs[(wm + m * 16 + l15) * 32 + l4 * 8];
            acc[m][0] = __builtin_amdgcn_mfma_f32_16x16x32_bf16(afr, bfr0, acc[m][0], 0, 0, 0);
            acc[m][1] = __builtin_amdgcn_mfma_f32_16x16x32_bf16(afr, bfr1, acc[m][1], 0, 0, 0);
        }
    }

    float* outn = out + (size_t)n * CO_ * P_;
    #pragma unroll
    for (int m = 0; m < 8; ++m) {
        int co = wm + m * 16 + l4 * 4;
        #pragma unroll
        for (int nn = 0; nn < 2; ++nn) {
            int p = p0 + wp + nn * 16 + l15;
            #pragma unroll
            for (int r = 0; r < 4; ++r) {
                outn[(size_t)(co + r) * P_ + p] = acc[m][nn][r];
            }
        }
    }
}

extern "C" void kernel_launch(void* const* d_in, const int* in_sizes, int n_in,
                              void* d_out, int out_size, void* d_ws, size_t ws_size,
                              hipStream_t stream) {
    const float* x      = (const float*)d_in[0];
    const float* offset = (const float*)d_in[1];
    const float* mask   = (const float*)d_in[2];
    const float* weight = (const float*)d_in[3];
    float* out = (float*)d_out;

    const size_t xT_elems = (size_t)N_ * P_ * C_;            // 8,388,608 ushort
    const size_t Wt_elems = (size_t)CO_ * CK_;               //   589,824 ushort
    const size_t need     = (xT_elems + Wt_elems) * sizeof(unsigned short); // 17,956,864 B

    if (ws_size >= need) {
        unsigned short* xT = (unsigned short*)d_ws;
        unsigned short* Wt = xT + xT_elems;
        transpose_x<<<dim3(P_ / 64, C_ / 64, N_), dim3(256), 0, stream>>>(x, xT);
        reorder_w<<<dim3(CO_), dim3(256), 0, stream>>>(weight, Wt);
        // grid: 8 n (XCD-pin) x 32 p-tiles = 256 blocks = 1 block/CU
        dcn_main<<<dim3((P_ / BN) * N_), dim3(NTHR), 0, stream>>>(xT, Wt, offset, mask, out);
    } else if (ws_size >= (8u << 20)) {
        dcn_fb<1><<<dim3(P_ / 128, N_), dim3(512), 0, stream>>>(x, offset, mask, weight, out);
    } else {
        dcn_fb<0><<<dim3(P_ / 128, N_), dim3(512), 0, stream>>>(x, offset, mask, weight, out);
    }
}

// Round 14
// 68.965 us; speedup vs baseline: 1.6914x; 1.0482x over previous
//
#include <hip/hip_runtime.h>
#include <hip/hip_bf16.h>
#include <hip/hip_fp16.h>
#include <stdint.h>

#define N_   8
#define C_   256
#define H_   64
#define W_   64
#define CO_  256
#define K_   9
#define HO_  64
#define WO_  64
#define CK_  (C_ * K_)    // 2304
#define P_   (HO_ * WO_)  // 4096

#define BN   128          // p per block
#define BK   64           // ck per K-step (2 MFMA K-slices)
#define NT   36           // K-steps: 9 taps x 4 channel-quarters
#define NTHR 1024         // 16 waves = 4 waves/SIMD

typedef __attribute__((ext_vector_type(8))) _Float16 f16x8;
typedef __attribute__((ext_vector_type(4))) float f32x4;

__device__ __forceinline__ unsigned short f2bf(float f) {
    uint32_t u = __builtin_bit_cast(uint32_t, f);
    uint32_t r = (u + 0x7FFFu + ((u >> 16) & 1u)) >> 16;
    return (unsigned short)r;
}
__device__ __forceinline__ float bf2f(unsigned short u) {
    return __builtin_bit_cast(float, (uint32_t)u << 16);
}
__device__ __forceinline__ unsigned short f2h(float f) {
    return __builtin_bit_cast(unsigned short, (_Float16)f);
}

// ================= FAST PATH (needs 17,956,864 B of d_ws) =================

// pre-pass A: x[n][c][hw] f32 -> xT[n][hw][c] f16
__global__ __launch_bounds__(256)
void transpose_x(const float* __restrict__ x, unsigned short* __restrict__ xT) {
    __shared__ float t[64][65];
    const int n  = blockIdx.z;
    const int c0 = blockIdx.y * 64;
    const int h0 = blockIdx.x * 64;
    const int tx = threadIdx.x & 63;
    const int ty = threadIdx.x >> 6;   // 0..3
    const float* xp = x + ((size_t)n * C_ + c0) * P_ + h0;
    #pragma unroll
    for (int i = 0; i < 16; ++i) {
        int c = ty * 16 + i;
        t[c][tx] = xp[(size_t)c * P_ + tx];
    }
    __syncthreads();
    unsigned short* op = xT + ((size_t)n * P_ + h0) * C_ + c0;
    #pragma unroll
    for (int i = 0; i < 16; ++i) {
        int hw = ty * 16 + i;
        op[(size_t)hw * C_ + tx] = f2h(t[tx][hw]);
    }
}

// pre-pass B: weight[co][c][k] f32 -> Wt[co][k][c] f16
__global__ __launch_bounds__(256)
void reorder_w(const float* __restrict__ w, unsigned short* __restrict__ Wt) {
    const int co = blockIdx.x;
    const int c  = threadIdx.x;
    const float* src = w + (size_t)co * CK_ + (size_t)c * K_;
    float v[9];
    #pragma unroll
    for (int k = 0; k < 9; ++k) v[k] = src[k];
    #pragma unroll
    for (int k = 0; k < 9; ++k)
        Wt[(size_t)co * CK_ + k * C_ + c] = f2h(v[k]);
}

// Raw-barrier helper: keeps in-flight vmem loads alive across the barrier
// (__syncthreads would force s_waitcnt vmcnt(0) first).
__device__ __forceinline__ void barrier_lgkm_only() {
    __builtin_amdgcn_sched_barrier(0);
    asm volatile("s_waitcnt lgkmcnt(0)" ::: "memory");
    __builtin_amdgcn_s_barrier();
    __builtin_amdgcn_sched_barrier(0);
}

// packed bilinear combine of one u32 (2 f16 channels) per corner
#define COMB(dst, A, B, Cc, D) do {                                   \
    __half2 _v = __hmul2(W0, __builtin_bit_cast(__half2, (A)));       \
    _v = __hfma2(W1, __builtin_bit_cast(__half2, (B)), _v);           \
    _v = __hfma2(W2, __builtin_bit_cast(__half2, (Cc)), _v);          \
    _v = __hfma2(W3, __builtin_bit_cast(__half2, (D)), _v);           \
    (dst) = __builtin_bit_cast(unsigned, _v); } while (0)

// Round 14: 1024-thread block (16 waves = 4 waves/SIMD). r13 post-mortem:
// wall 4300cy/iter vs pipes {MFMA 990, VALU 775, LDS ~1500} -> ~60% latency
// bubbles at 2 waves/SIMD. Same tile (256co x 128p), same double-buffered
// 1-barrier structure, same 126KB LDS; wave tile 32x64 (acc[2][4]),
// sampling 8ch/thread (prefetch regs 48->24, per-wave VALU halves).
// launch_bounds(1024,4): VGPR cap 128 — REQUIRED for 16 resident waves
// (waves/CU halves above 128 VGPR); live set ~105 so no spill expected.
__global__ __launch_bounds__(NTHR, 4)
void dcn_main(const unsigned short* __restrict__ xT,
              const unsigned short* __restrict__ Wt,
              const float* __restrict__ offset,
              const float* __restrict__ mask,
              float* __restrict__ out) {
    __shared__ uint2 sIdx[BN * K_];               //  9216 B (write-once)
    __shared__ uint4 sWd [BN * K_];               // 18432 B (write-once)
    __shared__ unsigned short sWs[2][CO_ * BK];   // 64 KB double-buffered
    __shared__ unsigned short sBs[2][BN * BK];    // 32 KB double-buffered -> 125952 B

    const int tid = threadIdx.x;
    // XCD-pin: bid%8 = XCD = batch image; per-XCD set ~3.2MB fits 4MB L2.
    const int bid = blockIdx.x;
    const int n   = bid & 7;
    const int p0  = (bid >> 3) * BN;   // 32 p-tiles per image

    for (int e = tid; e < BN * K_; e += NTHR) {
        int pl = e / K_;
        int k  = e - pl * K_;
        int p  = p0 + pl;
        int ho = p >> 6, wo = p & 63;
        float offy = offset[(size_t)((n * 2 * K_ + 2 * k)     * P_) + p];
        float offx = offset[(size_t)((n * 2 * K_ + 2 * k + 1) * P_) + p];
        float m    = mask  [(size_t)((n * K_ + k) * P_) + p];
        float py = (float)(k / 3 + ho - 1) + offy;
        float px = (float)(k % 3 + wo - 1) + offx;
        float y0f = floorf(py), x0f = floorf(px);
        float ly = py - y0f,   lx = px - x0f;
        int y0 = (int)y0f, x0 = (int)x0f;
        int y1 = y0 + 1,   x1 = x0 + 1;
        bool vy0 = (y0 >= 0) & (y0 < H_);
        bool vy1 = (y1 >= 0) & (y1 < H_);
        bool vx0 = (x0 >= 0) & (x0 < W_);
        bool vx1 = (x1 >= 0) & (x1 < W_);
        float w00 = (1.f - ly) * (1.f - lx) * m * ((vy0 & vx0) ? 1.f : 0.f);
        float w01 = (1.f - ly) * lx         * m * ((vy0 & vx1) ? 1.f : 0.f);
        float w10 = ly * (1.f - lx)         * m * ((vy1 & vx0) ? 1.f : 0.f);
        float w11 = ly * lx                 * m * ((vy1 & vx1) ? 1.f : 0.f);
        unsigned int cy0 = (unsigned)min(max(y0, 0), H_ - 1);
        unsigned int cy1 = (unsigned)min(max(y1, 0), H_ - 1);
        unsigned int cx0 = (unsigned)min(max(x0, 0), W_ - 1);
        unsigned int cx1 = (unsigned)min(max(x1, 0), W_ - 1);
        sIdx[e] = make_uint2((cy0 * W_ + cx0) | ((cy0 * W_ + cx1) << 16),
                             (cy1 * W_ + cx0) | ((cy1 * W_ + cx1) << 16));
        sWd[e] = make_uint4((unsigned)f2h(w00) * 0x10001u,
                            (unsigned)f2h(w01) * 0x10001u,
                            (unsigned)f2h(w10) * 0x10001u,
                            (unsigned)f2h(w11) * 0x10001u);
    }
    __syncthreads();   // params visible before prefetch(0) reads sIdx

    const unsigned short* xTn = xT + (size_t)n * P_ * C_;

    // ---- roles ----
    // sampling: 8 threads per p-row, 8 channels (16B) each
    const int spl = tid >> 3;                 // 0..127
    const int cs  = tid & 7;                  // channel slot (8 f16 = 16B)
    const int boff = spl * 128 + ((cs ^ (spl & 7)) << 4);
    // weight staging: 4 threads per co row, 2x 16B slots each
    const int wco  = tid >> 2;                // 0..255
    const int wsl  = tid & 3;                 // slots wsl and wsl+4
    const int wswz = wco & 7;
    const int woff = wco * 128;
    const unsigned short* wsrcbase = Wt + (size_t)wco * CK_ + wsl * 8;

    const int lane = tid & 63;
    const int wid  = tid >> 6;                // 0..15
    const int wm   = (wid & 7) * 32;          // 8 co-groups
    const int wp   = (wid >> 3) * 64;         // 2 p-groups
    const int l15  = lane & 15;
    const int l4   = lane >> 4;
    const int slA  = l4 ^ (l15 & 7);          // ks=0 slot; ks=1 -> ^4

    f32x4 acc[2][4] = {};

    // prefetch registers (one tile ahead, in flight across the barrier)
    uint4 qa, qb, qc, qd;    // 4 corners x 8 f16
    uint4 wq0, wq1;          // 2x 16B of weight row

#define PREF(TT) {                                                        \
        const int kn  = (TT) >> 2;                                        \
        const int c0n = ((TT) & 3) * 64;                                  \
        const unsigned short* ws = wsrcbase + kn * C_ + c0n;              \
        wq0 = *(const uint4*)(ws);                                        \
        wq1 = *(const uint4*)(ws + 32);                                   \
        uint2 id = sIdx[spl * K_ + kn];                                   \
        const unsigned short* base = xTn + c0n + cs * 8;                  \
        qa = *(const uint4*)(base + ((size_t)(id.x & 0xFFFFu) << 8));     \
        qb = *(const uint4*)(base + ((size_t)(id.x >> 16)     << 8));     \
        qc = *(const uint4*)(base + ((size_t)(id.y & 0xFFFFu) << 8));     \
        qd = *(const uint4*)(base + ((size_t)(id.y >> 16)     << 8));     \
    }

#define STAGE(TT, WB, BB) {                                               \
        char* wrB = (char*)(WB) + woff;                                   \
        *(uint4*)(wrB + ((wsl       ^ wswz) << 4)) = wq0;                 \
        *(uint4*)(wrB + (((wsl + 4) ^ wswz) << 4)) = wq1;                 \
        uint4 wv = sWd[spl * K_ + ((TT) >> 2)];                           \
        __half2 W0 = __builtin_bit_cast(__half2, wv.x);                   \
        __half2 W1 = __builtin_bit_cast(__half2, wv.y);                   \
        __half2 W2 = __builtin_bit_cast(__half2, wv.z);                   \
        __half2 W3 = __builtin_bit_cast(__half2, wv.w);                   \
        uint4 r;                                                          \
        COMB(r.x, qa.x, qb.x, qc.x, qd.x);                                \
        COMB(r.y, qa.y, qb.y, qc.y, qd.y);                                \
        COMB(r.z, qa.z, qb.z, qc.z, qd.z);                                \
        COMB(r.w, qa.w, qb.w, qc.w, qd.w);                                \
        *(uint4*)((char*)(BB) + boff) = r;                                \
    }

    // ---- prologue: tile 0 -> regs -> buf0; tile 1 -> regs ----
    PREF(0)
    STAGE(0, sWs[0], sBs[0])
    PREF(1)

    for (int t = 0; t < NT; ++t) {
        const int br = t & 1;
        const char* wR = (const char*)sWs[br];
        const char* bR = (const char*)sBs[br];

        // single barrier: buf[br] writes (last iter) visible; buf[br^1] reads
        // (last iter's MFMA) complete. In-flight global loads survive.
        barrier_lgkm_only();

        // ks=0 fragment reads (in regs across the stage)
        f16x8 A0, A1, B0, B1, B2, B3;
        {
            const int sl = slA;
            B0 = *(const f16x8*)(bR + (wp      + l15) * 128 + (sl << 4));
            B1 = *(const f16x8*)(bR + (wp + 16 + l15) * 128 + (sl << 4));
            B2 = *(const f16x8*)(bR + (wp + 32 + l15) * 128 + (sl << 4));
            B3 = *(const f16x8*)(bR + (wp + 48 + l15) * 128 + (sl << 4));
            A0 = *(const f16x8*)(wR + (wm      + l15) * 128 + (sl << 4));
            A1 = *(const f16x8*)(wR + (wm + 16 + l15) * 128 + (sl << 4));
        }

        // stage tile t+1 into the write buffer (different buffer -> no
        // second barrier); then issue tile t+2's global loads
        if (t + 1 < NT) {
            if (br) { STAGE(t + 1, sWs[0], sBs[0]) }
            else    { STAGE(t + 1, sWs[1], sBs[1]) }
            if (t + 2 < NT) PREF(t + 2)
        }

        // MFMA ks=0 (co-schedules with the ds_writes above)
        acc[0][0] = __builtin_amdgcn_mfma_f32_16x16x32_f16(A0, B0, acc[0][0], 0, 0, 0);
        acc[0][1] = __builtin_amdgcn_mfma_f32_16x16x32_f16(A0, B1, acc[0][1], 0, 0, 0);
        acc[0][2] = __builtin_amdgcn_mfma_f32_16x16x32_f16(A0, B2, acc[0][2], 0, 0, 0);
        acc[0][3] = __builtin_amdgcn_mfma_f32_16x16x32_f16(A0, B3, acc[0][3], 0, 0, 0);
        acc[1][0] = __builtin_amdgcn_mfma_f32_16x16x32_f16(A1, B0, acc[1][0], 0, 0, 0);
        acc[1][1] = __builtin_amdgcn_mfma_f32_16x16x32_f16(A1, B1, acc[1][1], 0, 0, 0);
        acc[1][2] = __builtin_amdgcn_mfma_f32_16x16x32_f16(A1, B2, acc[1][2], 0, 0, 0);
        acc[1][3] = __builtin_amdgcn_mfma_f32_16x16x32_f16(A1, B3, acc[1][3], 0, 0, 0);

        // ks=1 fragment reads + MFMA
        {
            const int sl = slA ^ 4;
            B0 = *(const f16x8*)(bR + (wp      + l15) * 128 + (sl << 4));
            B1 = *(const f16x8*)(bR + (wp + 16 + l15) * 128 + (sl << 4));
            B2 = *(const f16x8*)(bR + (wp + 32 + l15) * 128 + (sl << 4));
            B3 = *(const f16x8*)(bR + (wp + 48 + l15) * 128 + (sl << 4));
            A0 = *(const f16x8*)(wR + (wm      + l15) * 128 + (sl << 4));
            A1 = *(const f16x8*)(wR + (wm + 16 + l15) * 128 + (sl << 4));
        }
        acc[0][0] = __builtin_amdgcn_mfma_f32_16x16x32_f16(A0, B0, acc[0][0], 0, 0, 0);
        acc[0][1] = __builtin_amdgcn_mfma_f32_16x16x32_f16(A0, B1, acc[0][1], 0, 0, 0);
        acc[0][2] = __builtin_amdgcn_mfma_f32_16x16x32_f16(A0, B2, acc[0][2], 0, 0, 0);
        acc[0][3] = __builtin_amdgcn_mfma_f32_16x16x32_f16(A0, B3, acc[0][3], 0, 0, 0);
        acc[1][0] = __builtin_amdgcn_mfma_f32_16x16x32_f16(A1, B0, acc[1][0], 0, 0, 0);
        acc[1][1] = __builtin_amdgcn_mfma_f32_16x16x32_f16(A1, B1, acc[1][1], 0, 0, 0);
        acc[1][2] = __builtin_amdgcn_mfma_f32_16x16x32_f16(A1, B2, acc[1][2], 0, 0, 0);
        acc[1][3] = __builtin_amdgcn_mfma_f32_16x16x32_f16(A1, B3, acc[1][3], 0, 0, 0);
    }
#undef PREF
#undef STAGE

    float* outn = out + (size_t)n * CO_ * P_;
    #pragma unroll
    for (int m = 0; m < 2; ++m) {
        int co = wm + m * 16 + l4 * 4;
        #pragma unroll
        for (int nn = 0; nn < 4; ++nn) {
            int p = p0 + wp + nn * 16 + l15;
            #pragma unroll
            for (int r = 0; r < 4; ++r) {
                outn[(size_t)(co + r) * P_ + p] = acc[m][nn][r];
            }
        }
    }
}

// ================= FALLBACK (round-2 kernel, zero scratch, proven pass) =================
template <int TAG>
__global__ __launch_bounds__(512, 2)
void dcn_fb(const float* __restrict__ x,
            const float* __restrict__ offset,
            const float* __restrict__ mask,
            const float* __restrict__ weight,
            float* __restrict__ out) {
    typedef __attribute__((ext_vector_type(8))) short bf16x8;
    __shared__ uint2  sIdx[128 * K_];
    __shared__ float4 sW  [128 * K_];
    __shared__ unsigned short sWs[CO_ * 32];
    __shared__ unsigned short sBs[128 * 32];

    const int tid = threadIdx.x;
    const int n  = blockIdx.y;
    const int p0 = blockIdx.x * 128;

    for (int e = tid; e < 128 * K_; e += 512) {
        int pl = e / K_;
        int k  = e - pl * K_;
        int p  = p0 + pl;
        int ho = p >> 6, wo = p & 63;
        float offy = offset[(size_t)((n * 2 * K_ + 2 * k)     * P_) + p];
        float offx = offset[(size_t)((n * 2 * K_ + 2 * k + 1) * P_) + p];
        float m    = mask  [(size_t)((n * K_ + k) * P_) + p];
        float py = (float)(k / 3 + ho - 1) + offy;
        float px = (float)(k % 3 + wo - 1) + offx;
        float y0f = floorf(py), x0f = floorf(px);
        float ly = py - y0f,   lx = px - x0f;
        int y0 = (int)y0f, x0 = (int)x0f;
        int y1 = y0 + 1,   x1 = x0 + 1;
        bool vy0 = (y0 >= 0) & (y0 < H_);
        bool vy1 = (y1 >= 0) & (y1 < H_);
        bool vx0 = (x0 >= 0) & (x0 < W_);
        bool vx1 = (x1 >= 0) & (x1 < W_);
        float w00 = (1.f - ly) * (1.f - lx) * m * ((vy0 & vx0) ? 1.f : 0.f);
        float w01 = (1.f - ly) * lx         * m * ((vy0 & vx1) ? 1.f : 0.f);
        float w10 = ly * (1.f - lx)         * m * ((vy1 & vx0) ? 1.f : 0.f);
        float w11 = ly * lx                 * m * ((vy1 & vx1) ? 1.f : 0.f);
        unsigned int cy0 = (unsigned)min(max(y0, 0), H_ - 1);
        unsigned int cy1 = (unsigned)min(max(y1, 0), H_ - 1);
        unsigned int cx0 = (unsigned)min(max(x0, 0), W_ - 1);
        unsigned int cx1 = (unsigned)min(max(x1, 0), W_ - 1);
        sIdx[e] = make_uint2((cy0 * W_ + cx0) | ((cy0 * W_ + cx1) << 16),
                             (cy1 * W_ + cx0) | ((cy1 * W_ + cx1) << 16));
        sW[e]   = make_float4(w00, w01, w10, w11);
    }

    const float* xn = x + (size_t)n * C_ * P_;
    const int pl   = tid >> 2;
    const int pl9  = pl * K_;
    const int ckb  = (tid & 3) * 8;
    const int wco  = tid >> 1;
    const int wck  = (tid & 1) * 16;

    const int lane = tid & 63;
    const int wid  = tid >> 6;
    const int wm   = (wid & 1) * 128;
    const int wp   = (wid >> 1) * 32;
    const int l15  = lane & 15;
    const int l4   = lane >> 4;

    f32x4 acc[8][2] = {};

    for (int ck0 = 0; ck0 < CK_; ck0 += 32) {
        __syncthreads();
        {
            const float4* wsrc = (const float4*)(weight + (size_t)wco * CK_ + ck0 + wck);
            float4 wa = wsrc[0], wb = wsrc[1], wc = wsrc[2], wd = wsrc[3];
            uint4 q0, q1;
            q0.x = f2bf(wa.x) | ((unsigned)f2bf(wa.y) << 16);
            q0.y = f2bf(wa.z) | ((unsigned)f2bf(wa.w) << 16);
            q0.z = f2bf(wb.x) | ((unsigned)f2bf(wb.y) << 16);
            q0.w = f2bf(wb.z) | ((unsigned)f2bf(wb.w) << 16);
            q1.x = f2bf(wc.x) | ((unsigned)f2bf(wc.y) << 16);
            q1.y = f2bf(wc.z) | ((unsigned)f2bf(wc.w) << 16);
            q1.z = f2bf(wd.x) | ((unsigned)f2bf(wd.y) << 16);
            q1.w = f2bf(wd.z) | ((unsigned)f2bf(wd.w) << 16);
            *(uint4*)&sWs[wco * 32 + wck]     = q0;
            *(uint4*)&sWs[wco * 32 + wck + 8] = q1;
        }
        {
            int ckstart = ck0 + ckb;
            int cc = ckstart / 9;
            int kk = ckstart - cc * 9;
            unsigned int packed[4];
            unsigned short colv[8];
            #pragma unroll
            for (int j = 0; j < 8; ++j) {
                int e = pl9 + kk;
                uint2  id = sIdx[e];
                float4 wv = sW[e];
                const float* xp = xn + ((size_t)cc << 12);
                float v = wv.x * xp[id.x & 0xFFFFu]
                        + wv.y * xp[id.x >> 16]
                        + wv.z * xp[id.y & 0xFFFFu]
                        + wv.w * xp[id.y >> 16];
                colv[j] = f2bf(v);
                ++kk; if (kk == 9) { kk = 0; ++cc; }
            }
            packed[0] = colv[0] | ((unsigned)colv[1] << 16);
            packed[1] = colv[2] | ((unsigned)colv[3] << 16);
            packed[2] = colv[4] | ((unsigned)colv[5] << 16);
            packed[3] = colv[6] | ((unsigned)colv[7] << 16);
            *(uint4*)&sBs[pl * 32 + ckb] = *(uint4*)packed;
        }
        __syncthreads();
        bf16x8 bfr0 = *(const bf16x8*)&sBs[(wp + l15)      * 32 + l4 * 8];
        bf16x8 bfr1 = *(const bf16x8*)&sBs[(wp + 16 + l15) * 32 + l4 * 8];
        #pragma unroll
        for (int m = 0; m < 8; ++m) {
            bf16x8 afr = *(const bf16x8*)&sWs[(wm + m * 16 + l15) * 32 + l4 * 8];
            acc[m][0] = __builtin_amdgcn_mfma_f32_16x16x32_bf16(afr, bfr0, acc[m][0], 0, 0, 0);
            acc[m][1] = __builtin_amdgcn_mfma_f32_16x16x32_bf16(afr, bfr1, acc[m][1], 0, 0, 0);
        }
    }

    float* outn = out + (size_t)n * CO_ * P_;
    #pragma unroll
    for (int m = 0; m < 8; ++m) {
        int co = wm + m * 16 + l4 * 4;
        #pragma unroll
        for (int nn = 0; nn < 2; ++nn) {
            int p = p0 + wp + nn * 16 + l15;
            #pragma unroll
            for (int r = 0; r < 4; ++r) {
                outn[(size_t)(co + r) * P_ + p] = acc[m][nn][r];
            }
        }
    }
}

extern "C" void kernel_launch(void* const* d_in, const int* in_sizes, int n_in,
                              void* d_out, int out_size, void* d_ws, size_t ws_size,
                              hipStream_t stream) {
    const float* x      = (const float*)d_in[0];
    const float* offset = (const float*)d_in[1];
    const float* mask   = (const float*)d_in[2];
    const float* weight = (const float*)d_in[3];
    float* out = (float*)d_out;

    const size_t xT_elems = (size_t)N_ * P_ * C_;            // 8,388,608 ushort
    const size_t Wt_elems = (size_t)CO_ * CK_;               //   589,824 ushort
    const size_t need     = (xT_elems + Wt_elems) * sizeof(unsigned short); // 17,956,864 B

    if (ws_size >= need) {
        unsigned short* xT = (unsigned short*)d_ws;
        unsigned short* Wt = xT + xT_elems;
        transpose_x<<<dim3(P_ / 64, C_ / 64, N_), dim3(256), 0, stream>>>(x, xT);
        reorder_w<<<dim3(CO_), dim3(256), 0, stream>>>(weight, Wt);
        // grid: 8 n (XCD-pin) x 32 p-tiles = 256 blocks = 1 block/CU, 16 waves
        dcn_main<<<dim3((P_ / BN) * N_), dim3(NTHR), 0, stream>>>(xT, Wt, offset, mask, out);
    } else if (ws_size >= (8u << 20)) {
        dcn_fb<1><<<dim3(P_ / 128, N_), dim3(512), 0, stream>>>(x, offset, mask, weight, out);
    } else {
        dcn_fb<0><<<dim3(P_ / 128, N_), dim3(512), 0, stream>>>(x, offset, mask, weight, out);
    }
}